// Round 6
// baseline (119.878 us; speedup 1.0000x reference)
//
#include <hip/hip_runtime.h>
#include <hip/hip_bf16.h>
#include <cstddef>
#include <cstdint>
#include <cstring>

typedef __attribute__((ext_vector_type(8))) short bf16x8;
typedef __attribute__((ext_vector_type(4))) float f32x4;
typedef unsigned short ushort_t;

__device__ __forceinline__ ushort_t f2b(float f) {
    uint32_t x = __float_as_uint(f);
    uint32_t r = (x + 0x7FFFu + ((x >> 16) & 1u)) >> 16;   // RNE
    return (ushort_t)r;
}
__device__ __forceinline__ float b2f(ushort_t u) {
    return __uint_as_float(((uint32_t)u) << 16);
}
// packed 2xfp32 -> 2xbf16 via HW v_cvt_pk_bf16_f32
__device__ __forceinline__ uint32_t pk2(float x, float y) {
    __hip_bfloat162 h = __float22bfloat162_rn(float2{x, y});
    uint32_t u;
    __builtin_memcpy(&u, &h, 4);
    return u;
}

// ---------------------------------------------------------------------------
// prep: build all bf16-transposed weights + folded graph biases.
// ---------------------------------------------------------------------------
__global__ void prep_kernel(const float* __restrict__ m1_w, const float* __restrict__ m2_w,
                            const float* __restrict__ o1_w, const float* __restrict__ t1_w,
                            const float* __restrict__ t2_w,
                            const float* __restrict__ me_w, const float* __restrict__ mlp1_w,
                            const float* __restrict__ mlp2_w,
                            const float* __restrict__ te1_w, const float* __restrict__ te2_w,
                            const float* __restrict__ te3_w,
                            const float* __restrict__ graph_fts,
                            const float* __restrict__ mg_w, const float* __restrict__ mg_b,
                            const float* __restrict__ m1_b,
                            const float* __restrict__ tg_w, const float* __restrict__ t2_b,
                            const float* __restrict__ tg_b,
                            ushort_t* __restrict__ Wnt,
                            ushort_t* __restrict__ Wme, ushort_t* __restrict__ Wm1,
                            ushort_t* __restrict__ Wm2, ushort_t* __restrict__ TEt,
                            float* __restrict__ G1, float* __restrict__ TG) {
    int idx = blockIdx.x * 256 + threadIdx.x;
    if (idx < 106496) {                       // Wnt: o*256 + k
        int o = idx >> 8, k = idx & 255;
        float v = 0.0f;
        if (o < 128)       v = m1_w[k * 128 + o];
        else if (o < 256)  v = m2_w[k * 128 + (o - 128)];
        else if (o < 384)  v = o1_w[k * 128 + (o - 256)];
        else if (o < 392)  v = t1_w[k * 8 + (o - 384)];
        else if (o < 400)  v = t2_w[k * 8 + (o - 392)];
        Wnt[idx] = f2b(v);
    } else if (idx < 122880) {
        int t = idx - 106496, o = t >> 7, h = t & 127;
        Wme[t] = f2b(me_w[h * 128 + o]);
    } else if (idx < 139264) {
        int t = idx - 122880, o = t >> 7, h = t & 127;
        Wm1[t] = f2b(mlp1_w[h * 128 + o]);
    } else if (idx < 155648) {
        int t = idx - 139264, o = t >> 7, h = t & 127;
        Wm2[t] = f2b(mlp2_w[h * 128 + o]);
    } else if (idx < 159744) {
        int t = idx - 155648, c = t >> 7, h = t & 127;
        float v = 0.0f;
        if (c < 8)       v = te1_w[h * 8 + c];
        else if (c < 16) v = te2_w[h * 8 + (c - 8)];
        else if (c < 24) v = te3_w[h * 8 + (c - 16)];
        TEt[t] = f2b(v);
    } else if (idx < 160256) {                // G1
        int t = idx - 159744, b = t >> 7, h = t & 127;
        float a = m1_b[h] + mg_b[h];
        #pragma unroll 4
        for (int k = 0; k < 128; k++) a = fmaf(graph_fts[b * 128 + k], mg_w[k * 128 + h], a);
        G1[t] = a;
    } else if (idx < 160288) {                // TG
        int t = idx - 160256, b = t >> 3, tt = t & 7;
        float a = t2_b[tt] + tg_b[tt];
        #pragma unroll 4
        for (int k = 0; k < 128; k++) a = fmaf(graph_fts[b * 128 + k], tg_w[k * 8 + tt], a);
        TG[t] = a;
    }
}

// ---------------------------------------------------------------------------
// node GEMM (MFMA bf16): Z[512x256] @ Wnt^T -> {M1,M2,O1z,T1v,TT2}
// ---------------------------------------------------------------------------
__global__ __launch_bounds__(256)
void node_gemm(const float* __restrict__ node_fts, const float* __restrict__ hidden,
               const ushort_t* __restrict__ Wnt,
               const float* __restrict__ G1, const float* __restrict__ m2_b,
               const float* __restrict__ o1_b, const float* __restrict__ t1_b,
               const float* __restrict__ TG,
               float* __restrict__ M1, float* __restrict__ M2, float* __restrict__ O1z,
               float* __restrict__ T1v, float* __restrict__ TT2) {
    __shared__ ushort_t Zs[32 * 256];         // 16 KB, swizzled
    char* Zb = (char*)Zs;
    const int tid = threadIdx.x;
    const int blk = blockIdx.x;               // 16 blocks
    const int b = blk >> 2, q = blk & 3;
    const int row0 = b * 128 + q * 32;
    const int w = tid >> 6, l = tid & 63, g = l >> 4, lq = l & 15;

    const float4* nsrc = reinterpret_cast<const float4*>(node_fts + (size_t)row0 * 128);
    const float4* hsrc = reinterpret_cast<const float4*>(hidden + (size_t)row0 * 128);
    #pragma unroll
    for (int p = 0; p < 8; p++) {
        int idx = tid + p * 256;
        int r = idx >> 6, c4 = idx & 63;
        float4 v = (c4 < 32) ? nsrc[r * 32 + c4] : hsrc[r * 32 + (c4 - 32)];
        uint2 pk;
        pk.x = pk2(v.x, v.y);
        pk.y = pk2(v.z, v.w);
        *reinterpret_cast<uint2*>(Zb + r * 512 + (((c4 >> 1) ^ (r & 7)) << 4) + (c4 & 1) * 8) = pk;
    }
    __syncthreads();

    for (int mt = w; mt < 26; mt += 4) {
        f32x4 acc0 = (f32x4){0.f, 0.f, 0.f, 0.f};
        f32x4 acc1 = (f32x4){0.f, 0.f, 0.f, 0.f};
        const ushort_t* arow = Wnt + (size_t)(mt * 16 + lq) * 256;
        #pragma unroll
        for (int ks = 0; ks < 8; ks++) {
            bf16x8 a = *reinterpret_cast<const bf16x8*>(arow + ks * 32 + g * 8);
            int j0 = lq, j1 = 16 + lq;
            bf16x8 b0 = *reinterpret_cast<const bf16x8*>(Zb + j0 * 512 + (((ks * 4 + g) ^ (j0 & 7)) << 4));
            bf16x8 b1 = *reinterpret_cast<const bf16x8*>(Zb + j1 * 512 + (((ks * 4 + g) ^ (j1 & 7)) << 4));
            acc0 = __builtin_amdgcn_mfma_f32_16x16x32_bf16(a, b0, acc0, 0, 0, 0);
            acc1 = __builtin_amdgcn_mfma_f32_16x16x32_bf16(a, b1, acc1, 0, 0, 0);
        }
        #pragma unroll
        for (int half = 0; half < 2; half++) {
            const f32x4 acc = half ? acc1 : acc0;
            const int grow = row0 + half * 16 + lq;
            #pragma unroll
            for (int c = 0; c < 4; c++) {
                int o = mt * 16 + g * 4 + c;
                float v = acc[c];
                if (o < 128)       M1[(size_t)grow * 128 + o] = v + G1[b * 128 + o];
                else if (o < 256)  M2[(size_t)grow * 128 + (o - 128)] = v + m2_b[o - 128];
                else if (o < 384)  O1z[(size_t)grow * 128 + (o - 256)] = v + o1_b[o - 256];
                else if (o < 392)  T1v[(size_t)grow * 8 + (o - 384)] = v + t1_b[o - 384];
                else if (o < 400)  TT2[(size_t)grow * 8 + (o - 392)] = v + TG[b * 8 + (o - 392)];
            }
        }
    }
}

// ---------------------------------------------------------------------------
// edge kernel, MFMA bf16. 1024 blocks = (b, ie, j-half): 64 rows each.
// Ping-pong double-buffered LDS X (2 x 16 KB), 4 barriers total.
// Waves: o_blk=(w&1)*64, j_blk=(w>>1)*32 -> 4x2 fragments per wave.
// ---------------------------------------------------------------------------
__device__ __forceinline__ void mm64(const ushort_t* __restrict__ Wt, const char* Xa,
                                     f32x4 acc[4][2], int o_blk, int j_blk, int g, int lq) {
    #pragma unroll
    for (int ks = 0; ks < 4; ks++) {
        bf16x8 a[4], bb[2];
        #pragma unroll
        for (int m = 0; m < 4; m++)
            a[m] = *reinterpret_cast<const bf16x8*>(Wt + (size_t)(o_blk + m * 16 + lq) * 128 + ks * 32 + g * 8);
        #pragma unroll
        for (int n = 0; n < 2; n++) {
            int j = j_blk + n * 16 + lq;
            bb[n] = *reinterpret_cast<const bf16x8*>(Xa + j * 256 + (((ks * 4 + g) ^ (j & 7)) << 4));
        }
        #pragma unroll
        for (int m = 0; m < 4; m++)
            #pragma unroll
            for (int n = 0; n < 2; n++)
                acc[m][n] = __builtin_amdgcn_mfma_f32_16x16x32_bf16(a[m], bb[n], acc[m][n], 0, 0, 0);
    }
}

__global__ __launch_bounds__(256, 4)
void edge_kernel(const float* __restrict__ edge_fts,
                 const ushort_t* __restrict__ Wme, const float* __restrict__ me_b,
                 const ushort_t* __restrict__ Wm1, const float* __restrict__ mlp1_b,
                 const ushort_t* __restrict__ Wm2, const float* __restrict__ mlp2_b,
                 const ushort_t* __restrict__ TEt,
                 const float* __restrict__ te1_b, const float* __restrict__ te2_b,
                 const float* __restrict__ te3_b,
                 const float* __restrict__ M1,  const float* __restrict__ M2,
                 const float* __restrict__ T1v, const float* __restrict__ TT2,
                 ushort_t* __restrict__ msgsM, float* __restrict__ T1buf,
                 float* __restrict__ T2buf, float* __restrict__ E3buf) {
    __shared__ ushort_t Xs[2][8192];   // 2 x 16 KB bf16 tiles, swizzled
    char* X0 = (char*)Xs[0];
    char* X1 = (char*)Xs[1];
    const int tid = threadIdx.x;
    const int b  = blockIdx.x >> 8;
    const int ie = (blockIdx.x >> 1) & 127;
    const int jrow0 = (blockIdx.x & 1) * 64;
    const int w = tid >> 6, l = tid & 63, g = l >> 4, lq = l & 15;
    const int o_blk = (w & 1) * 64, j_blk = (w >> 1) * 32;

    // ---- stage 0: global fp32 -> bf16 swizzled LDS (64 rows) ----
    const float4* esrc = reinterpret_cast<const float4*>(
        edge_fts + ((size_t)(b * 128 + ie) * 128 + jrow0) * 128);
    #pragma unroll
    for (int p = 0; p < 8; p++) {
        int idx = tid + p * 256;           // float4 index 0..2047
        int r = idx >> 5, c4 = idx & 31;
        float4 v = esrc[idx];
        uint2 pk;
        pk.x = pk2(v.x, v.y);
        pk.y = pk2(v.z, v.w);
        *reinterpret_cast<uint2*>(X0 + r * 256 + (((c4 >> 1) ^ (r & 7)) << 4) + (c4 & 1) * 8) = pk;
    }
    __syncthreads();

    // ---- te projections (read X0) ----
    {
        const int m_te = w & 1;
        const ushort_t* At = TEt + m_te * 16 * 128;
        f32x4 acc2[2];
        #pragma unroll
        for (int n = 0; n < 2; n++) acc2[n] = (f32x4){0.f, 0.f, 0.f, 0.f};
        #pragma unroll
        for (int ks = 0; ks < 4; ks++) {
            bf16x8 a = *reinterpret_cast<const bf16x8*>(At + lq * 128 + ks * 32 + g * 8);
            #pragma unroll
            for (int n = 0; n < 2; n++) {
                int j = j_blk + n * 16 + lq;
                bf16x8 bbv = *reinterpret_cast<const bf16x8*>(X0 + j * 256 + (((ks * 4 + g) ^ (j & 7)) << 4));
                acc2[n] = __builtin_amdgcn_mfma_f32_16x16x32_bf16(a, bbv, acc2[n], 0, 0, 0);
            }
        }
        if (m_te == 0) {
            if (g < 2) {   // te1: T1buf[b][jg][ie][t] (+T1v[b,ie])
                int t0 = g * 4;
                const float4 eb = *reinterpret_cast<const float4*>(te1_b + t0);
                const float4 tv = *reinterpret_cast<const float4*>(T1v + (size_t)(b * 128 + ie) * 8 + t0);
                #pragma unroll
                for (int n = 0; n < 2; n++) {
                    int jg = jrow0 + j_blk + n * 16 + lq;
                    float4 o4 = make_float4(acc2[n][0] + eb.x + tv.x, acc2[n][1] + eb.y + tv.y,
                                            acc2[n][2] + eb.z + tv.z, acc2[n][3] + eb.w + tv.w);
                    *reinterpret_cast<float4*>(T1buf + ((size_t)(b * 128 + jg) * 128 + ie) * 8 + t0) = o4;
                }
            } else {       // te2: T2buf[b][ie][jg][t]
                int t0 = g * 4 - 8;
                const float4 eb = *reinterpret_cast<const float4*>(te2_b + t0);
                #pragma unroll
                for (int n = 0; n < 2; n++) {
                    int jg = jrow0 + j_blk + n * 16 + lq;
                    float4 o4 = make_float4(acc2[n][0] + eb.x, acc2[n][1] + eb.y,
                                            acc2[n][2] + eb.z, acc2[n][3] + eb.w);
                    *reinterpret_cast<float4*>(T2buf + ((size_t)(b * 128 + ie) * 128 + jg) * 8 + t0) = o4;
                }
            }
        } else if (g < 2) { // te3: E3buf[b][ie][jg][t] + TT2[b,ie] + T1v[b,jg]
            int t0 = g * 4;
            const float4 eb = *reinterpret_cast<const float4*>(te3_b + t0);
            const float4 t2v = *reinterpret_cast<const float4*>(TT2 + (size_t)(b * 128 + ie) * 8 + t0);
            #pragma unroll
            for (int n = 0; n < 2; n++) {
                int jg = jrow0 + j_blk + n * 16 + lq;
                const float4 t3v = *reinterpret_cast<const float4*>(T1v + (size_t)(b * 128 + jg) * 8 + t0);
                float4 o4 = make_float4(acc2[n][0] + eb.x + t2v.x + t3v.x,
                                        acc2[n][1] + eb.y + t2v.y + t3v.y,
                                        acc2[n][2] + eb.z + t2v.z + t3v.z,
                                        acc2[n][3] + eb.w + t2v.w + t3v.w);
                *reinterpret_cast<float4*>(E3buf + ((size_t)(b * 128 + ie) * 128 + jg) * 8 + t0) = o4;
            }
        }
    }

    f32x4 acc[4][2];

    // ================= stage 1: X1 = relu(X0@me_w + me_b + M1[b,jg] + M2[b,ie]) =================
    #pragma unroll
    for (int m = 0; m < 4; m++)
        #pragma unroll
        for (int n = 0; n < 2; n++) acc[m][n] = (f32x4){0.f, 0.f, 0.f, 0.f};
    mm64(Wme, X0, acc, o_blk, j_blk, g, lq);
    {
        float4 bc[4];
        #pragma unroll
        for (int m = 0; m < 4; m++) {
            int o0 = o_blk + m * 16 + g * 4;
            const float4 eb = *reinterpret_cast<const float4*>(me_b + o0);
            const float4 m2 = *reinterpret_cast<const float4*>(M2 + (size_t)(b * 128 + ie) * 128 + o0);
            bc[m] = make_float4(eb.x + m2.x, eb.y + m2.y, eb.z + m2.z, eb.w + m2.w);
        }
        #pragma unroll
        for (int m = 0; m < 4; m++) {
            int o0 = o_blk + m * 16 + g * 4;
            #pragma unroll
            for (int n = 0; n < 2; n++) {
                int j = j_blk + n * 16 + lq;
                int jg = jrow0 + j;
                const float4 m1 = *reinterpret_cast<const float4*>(M1 + (size_t)(b * 128 + jg) * 128 + o0);
                float r0 = fmaxf(acc[m][n][0] + bc[m].x + m1.x, 0.f);
                float r1 = fmaxf(acc[m][n][1] + bc[m].y + m1.y, 0.f);
                float r2 = fmaxf(acc[m][n][2] + bc[m].z + m1.z, 0.f);
                float r3 = fmaxf(acc[m][n][3] + bc[m].w + m1.w, 0.f);
                uint2 pk;
                pk.x = pk2(r0, r1);
                pk.y = pk2(r2, r3);
                *reinterpret_cast<uint2*>(X1 + j * 256 + ((((o0 >> 3) ^ (j & 7))) << 4) + (o0 & 7) * 2) = pk;
            }
        }
        __syncthreads();
    }

    // ================= stage 2: X0 = relu(X1@mlp1_w + mlp1_b) =================
    #pragma unroll
    for (int m = 0; m < 4; m++)
        #pragma unroll
        for (int n = 0; n < 2; n++) acc[m][n] = (f32x4){0.f, 0.f, 0.f, 0.f};
    mm64(Wm1, X1, acc, o_blk, j_blk, g, lq);
    {
        #pragma unroll
        for (int m = 0; m < 4; m++) {
            int o0 = o_blk + m * 16 + g * 4;
            const float4 bb = *reinterpret_cast<const float4*>(mlp1_b + o0);
            #pragma unroll
            for (int n = 0; n < 2; n++) {
                int j = j_blk + n * 16 + lq;
                float r0 = fmaxf(acc[m][n][0] + bb.x, 0.f);
                float r1 = fmaxf(acc[m][n][1] + bb.y, 0.f);
                float r2 = fmaxf(acc[m][n][2] + bb.z, 0.f);
                float r3 = fmaxf(acc[m][n][3] + bb.w, 0.f);
                uint2 pk;
                pk.x = pk2(r0, r1);
                pk.y = pk2(r2, r3);
                *reinterpret_cast<uint2*>(X0 + j * 256 + ((((o0 >> 3) ^ (j & 7))) << 4) + (o0 & 7) * 2) = pk;
            }
        }
        __syncthreads();
    }

    // ================= stage 3: X1 = X0@mlp2_w + mlp2_b (no relu) =================
    #pragma unroll
    for (int m = 0; m < 4; m++)
        #pragma unroll
        for (int n = 0; n < 2; n++) acc[m][n] = (f32x4){0.f, 0.f, 0.f, 0.f};
    mm64(Wm2, X0, acc, o_blk, j_blk, g, lq);
    {
        #pragma unroll
        for (int m = 0; m < 4; m++) {
            int o0 = o_blk + m * 16 + g * 4;
            const float4 bb = *reinterpret_cast<const float4*>(mlp2_b + o0);
            #pragma unroll
            for (int n = 0; n < 2; n++) {
                int j = j_blk + n * 16 + lq;
                float r0 = acc[m][n][0] + bb.x;
                float r1 = acc[m][n][1] + bb.y;
                float r2 = acc[m][n][2] + bb.z;
                float r3 = acc[m][n][3] + bb.w;
                uint2 pk;
                pk.x = pk2(r0, r1);
                pk.y = pk2(r2, r3);
                *reinterpret_cast<uint2*>(X1 + j * 256 + ((((o0 >> 3) ^ (j & 7))) << 4) + (o0 & 7) * 2) = pk;
            }
        }
        __syncthreads();
    }

    // ---- de-swizzle copy-out: msgsM[b][jg][i=ie][h] bf16 ----
    {
        const int r0 = tid >> 4, sc = tid & 15;
        #pragma unroll
        for (int q = 0; q < 4; q++) {
            int r = r0 + q * 16;
            uint4 v = *reinterpret_cast<const uint4*>(X1 + r * 256 + sc * 16);
            int logical = sc ^ (r & 7);
            *reinterpret_cast<uint4*>(msgsM + ((size_t)(b * 128 + jrow0 + r) * 128 + ie) * 128 + logical * 8) = v;
        }
    }
}

// ---------------------------------------------------------------------------
// masked max aggregation (msgsM[b][j][i][h] bf16, contiguous per (b,j)) + head
// ---------------------------------------------------------------------------
__global__ __launch_bounds__(256)
void agg_out_kernel(const ushort_t* __restrict__ msgsM, const int* __restrict__ adj,
                    const float* __restrict__ O1z,
                    const float* __restrict__ o2_w, const float* __restrict__ o2_b,
                    const float* __restrict__ scale, const float* __restrict__ bias,
                    float* __restrict__ out) {
    __shared__ float aggs[4][128];
    __shared__ float fagg[128];
    __shared__ float red[2][2];
    const int b = blockIdx.x >> 7, j = blockIdx.x & 127;
    const int t = threadIdx.x;
    const int wv = t >> 6, ln = t & 63;
    const ushort_t* msrc = msgsM + (size_t)(b * 128 + j) * 16384;
    const int* arow = adj + b * 16384 + j;
    float a0 = -1e9f, a1 = -1e9f;
    #pragma unroll 8
    for (int s = 0; s < 32; s++) {
        const int i = s * 4 + wv;
        uint32_t u = *reinterpret_cast<const uint32_t*>(msrc + i * 128 + ln * 2);
        bool m = (arow[i * 128] == 1);
        float x0 = b2f((ushort_t)(u & 0xffffu));
        float x1 = b2f((ushort_t)(u >> 16));
        a0 = m ? fmaxf(a0, x0) : a0;
        a1 = m ? fmaxf(a1, x1) : a1;
    }
    aggs[wv][ln * 2]     = a0;
    aggs[wv][ln * 2 + 1] = a1;
    __syncthreads();
    if (t < 128)
        fagg[t] = fmaxf(fmaxf(aggs[0][t], aggs[1][t]), fmaxf(aggs[2][t], aggs[3][t]));
    __syncthreads();

    float v = 0.0f;
    if (t < 128) {
        float val = o2_b[t] + O1z[(size_t)(b * 128 + j) * 128 + t];
        #pragma unroll 4
        for (int k = 0; k < 128; k++) val = fmaf(fagg[k], o2_w[k * 128 + t], val);
        v = fmaxf(val, 0.0f);
    }
    float s = v, s2 = v * v;
    #pragma unroll
    for (int off = 32; off >= 1; off >>= 1) {
        s += __shfl_down(s, off, 64);
        s2 += __shfl_down(s2, off, 64);
    }
    if (t < 128 && (t & 63) == 0) { red[t >> 6][0] = s; red[t >> 6][1] = s2; }
    __syncthreads();
    if (t < 128) {
        const float tot = red[0][0] + red[1][0];
        const float tot2 = red[0][1] + red[1][1];
        const float mean = tot * (1.0f / 128.0f);
        const float var = tot2 * (1.0f / 128.0f) - mean * mean;
        const float rstd = rsqrtf(var + 1e-5f);
        out[(size_t)(b * 128 + j) * 128 + t] = (v - mean) * rstd * scale[t] + bias[t];
    }
}

// ---------------------------------------------------------------------------
// triplet kernel: 1 jf per block, 512 threads (8 waves).
// ---------------------------------------------------------------------------
__global__ __launch_bounds__(512)
void tri_kernel(const float* __restrict__ T1buf, const float* __restrict__ T2buf,
                const float* __restrict__ E3buf, const float* __restrict__ o3_w,
                const float* __restrict__ o3_b, const float* __restrict__ scale,
                const float* __restrict__ bias, float* __restrict__ tri_out) {
    __shared__ __align__(16) float T1s[1024];
    __shared__ __align__(16) float E3s[1024];
    __shared__ __align__(16) float o3s[1024];
    __shared__ __align__(16) float Ps[4][128][8];
    const int b = blockIdx.x >> 7, jf = blockIdx.x & 127;
    const int tid = threadIdx.x;
    if (tid < 256) {
        reinterpret_cast<float4*>(T1s)[tid] =
            reinterpret_cast<const float4*>(T1buf + (size_t)(b * 128 + jf) * 1024)[tid];
        reinterpret_cast<float4*>(o3s)[tid] = reinterpret_cast<const float4*>(o3_w)[tid];
    } else {
        int t2 = tid - 256;
        reinterpret_cast<float4*>(E3s)[t2] =
            reinterpret_cast<const float4*>(E3buf + (size_t)(b * 128 + jf) * 1024)[t2];
    }
    __syncthreads();

    {
        const int kf = tid & 127, ih = tid >> 7;      // ih 0..3
        float a8[8];
        #pragma unroll
        for (int t = 0; t < 8; t++) a8[t] = -3.0e38f;
        const float4* t2p = reinterpret_cast<const float4*>(T2buf + (size_t)b * 131072);
        #pragma unroll 4
        for (int ii = 0; ii < 32; ++ii) {
            const int i = ih * 32 + ii;
            const float4 p = t2p[(i * 128 + kf) * 2];
            const float4 q = t2p[(i * 128 + kf) * 2 + 1];
            const float* t1r = &T1s[i * 8];
            a8[0] = fmaxf(a8[0], t1r[0] + p.x);
            a8[1] = fmaxf(a8[1], t1r[1] + p.y);
            a8[2] = fmaxf(a8[2], t1r[2] + p.z);
            a8[3] = fmaxf(a8[3], t1r[3] + p.w);
            a8[4] = fmaxf(a8[4], t1r[4] + q.x);
            a8[5] = fmaxf(a8[5], t1r[5] + q.y);
            a8[6] = fmaxf(a8[6], t1r[6] + q.z);
            a8[7] = fmaxf(a8[7], t1r[7] + q.w);
        }
        #pragma unroll
        for (int t = 0; t < 8; t++) Ps[ih][kf][t] = a8[t];
    }
    __syncthreads();

    const int w = tid >> 6, l = tid & 63;
    const float ob0 = o3_b[l],     ob1 = o3_b[l + 64];
    const float sc0 = scale[l],    sc1 = scale[l + 64];
    const float bi0 = bias[l],     bi1 = bias[l + 64];
    for (int kk = 0; kk < 16; ++kk) {
        const int kf = w * 16 + kk;
        float m8[8];
        #pragma unroll
        for (int t = 0; t < 8; t++)
            m8[t] = fmaxf(fmaxf(Ps[0][kf][t], Ps[1][kf][t]),
                          fmaxf(Ps[2][kf][t], Ps[3][kf][t])) + E3s[kf * 8 + t];
        float v0 = ob0, v1 = ob1;
        #pragma unroll
        for (int t = 0; t < 8; t++) {
            v0 = fmaf(m8[t], o3s[t * 128 + l], v0);
            v1 = fmaf(m8[t], o3s[t * 128 + l + 64], v1);
        }
        v0 = fmaxf(v0, 0.0f);
        v1 = fmaxf(v1, 0.0f);
        float s = v0 + v1, s2 = v0 * v0 + v1 * v1;
        #pragma unroll
        for (int off = 32; off >= 1; off >>= 1) {
            s  += __shfl_xor(s, off, 64);
            s2 += __shfl_xor(s2, off, 64);
        }
        const float mean = s * (1.0f / 128.0f);
        const float var = s2 * (1.0f / 128.0f) - mean * mean;
        const float rstd = rsqrtf(var + 1e-5f);
        float* dst = tri_out + (size_t)((b * 128 + jf) * 128 + kf) * 128;
        dst[l]      = (v0 - mean) * rstd * sc0 + bi0;
        dst[l + 64] = (v1 - mean) * rstd * sc1 + bi1;
    }
}

// ---------------------------------------------------------------------------
extern "C" void kernel_launch(void* const* d_in, const int* in_sizes, int n_in,
                              void* d_out, int out_size, void* d_ws, size_t ws_size,
                              hipStream_t stream) {
    const float* node_fts  = (const float*)d_in[0];
    const float* edge_fts  = (const float*)d_in[1];
    const float* graph_fts = (const float*)d_in[2];
    const float* hidden    = (const float*)d_in[3];
    const int*   adj       = (const int*)d_in[4];
    const float* m1_w = (const float*)d_in[5],  *m1_b = (const float*)d_in[6];
    const float* m2_w = (const float*)d_in[7],  *m2_b = (const float*)d_in[8];
    const float* me_w = (const float*)d_in[9],  *me_b = (const float*)d_in[10];
    const float* mg_w = (const float*)d_in[11], *mg_b = (const float*)d_in[12];
    const float* mlp1_w = (const float*)d_in[13], *mlp1_b = (const float*)d_in[14];
    const float* mlp2_w = (const float*)d_in[15], *mlp2_b = (const float*)d_in[16];
    const float* o1_w = (const float*)d_in[17], *o1_b = (const float*)d_in[18];
    const float* o2_w = (const float*)d_in[19], *o2_b = (const float*)d_in[20];
    const float* t1_w = (const float*)d_in[21], *t1_b = (const float*)d_in[22];
    const float* t2_w = (const float*)d_in[23], *t2_b = (const float*)d_in[24];
    const float* te1_w = (const float*)d_in[25], *te1_b = (const float*)d_in[26];
    const float* te2_w = (const float*)d_in[27], *te2_b = (const float*)d_in[28];
    const float* te3_w = (const float*)d_in[29], *te3_b = (const float*)d_in[30];
    const float* tg_w = (const float*)d_in[31], *tg_b = (const float*)d_in[32];
    const float* o3_w = (const float*)d_in[33], *o3_b = (const float*)d_in[34];
    const float* norm_scale = (const float*)d_in[35];
    const float* norm_bias  = (const float*)d_in[36];

    char* w8 = (char*)d_ws;
    float*    M1    = (float*)(w8 + 0);          // 256 KB
    float*    M2    = (float*)(w8 + 262144);     // 256 KB
    float*    O1z   = (float*)(w8 + 524288);     // 256 KB
    float*    T1v   = (float*)(w8 + 786432);     // 16 KB
    float*    TT2   = (float*)(w8 + 802816);     // 16 KB
    ushort_t* Wme   = (ushort_t*)(w8 + 819200);  // 32 KB
    ushort_t* Wm1   = (ushort_t*)(w8 + 851968);  // 32 KB
    ushort_t* Wm2   = (ushort_t*)(w8 + 884736);  // 32 KB
    ushort_t* TEt   = (ushort_t*)(w8 + 917504);  // 8 KB
    ushort_t* msgsM = (ushort_t*)(w8 + 925696);  // 16 MB
    float*    T1buf = (float*)(w8 + 17702912);   // 2 MB
    float*    T2buf = (float*)(w8 + 19800064);   // 2 MB
    float*    E3buf = (float*)(w8 + 21897216);   // 2 MB
    ushort_t* Wnt   = (ushort_t*)(w8 + 23994368);// 208 KB
    float*    G1    = (float*)(w8 + 24207360);   // 2 KB
    float*    TG    = (float*)(w8 + 24209408);   // 128 B

    float* out_p  = (float*)d_out;            // [4,128,128]
    float* tri_p  = (float*)d_out + 65536;    // [4,128,128,128]

    prep_kernel<<<627, 256, 0, stream>>>(m1_w, m2_w, o1_w, t1_w, t2_w,
                                         me_w, mlp1_w, mlp2_w, te1_w, te2_w, te3_w,
                                         graph_fts, mg_w, mg_b, m1_b, tg_w, t2_b, tg_b,
                                         Wnt, Wme, Wm1, Wm2, TEt, G1, TG);
    node_gemm<<<16, 256, 0, stream>>>(node_fts, hidden, Wnt, G1, m2_b, o1_b, t1_b, TG,
                                      M1, M2, O1z, T1v, TT2);
    edge_kernel<<<1024, 256, 0, stream>>>(edge_fts, Wme, me_b, Wm1, mlp1_b, Wm2, mlp2_b,
                                          TEt, te1_b, te2_b, te3_b,
                                          M1, M2, T1v, TT2, msgsM, T1buf, T2buf, E3buf);
    agg_out_kernel<<<512, 256, 0, stream>>>(msgsM, adj, O1z, o2_w, o2_b,
                                            norm_scale, norm_bias, out_p);
    tri_kernel<<<512, 512, 0, stream>>>(T1buf, T2buf, E3buf, o3_w, o3_b,
                                        norm_scale, norm_bias, tri_p);
}

// Round 7
// 109.763 us; speedup vs baseline: 1.0922x; 1.0922x over previous
//
#include <hip/hip_runtime.h>
#include <hip/hip_bf16.h>
#include <cstddef>
#include <cstdint>
#include <cstring>

typedef __attribute__((ext_vector_type(8))) short bf16x8;
typedef __attribute__((ext_vector_type(4))) float f32x4;
typedef unsigned short ushort_t;

__device__ __forceinline__ ushort_t f2b(float f) {
    uint32_t x = __float_as_uint(f);
    uint32_t r = (x + 0x7FFFu + ((x >> 16) & 1u)) >> 16;   // RNE
    return (ushort_t)r;
}
__device__ __forceinline__ float b2f(ushort_t u) {
    return __uint_as_float(((uint32_t)u) << 16);
}
// packed 2xfp32 -> 2xbf16 via HW v_cvt_pk_bf16_f32
__device__ __forceinline__ uint32_t pk2(float x, float y) {
    __hip_bfloat162 h = __float22bfloat162_rn(float2{x, y});
    uint32_t u;
    __builtin_memcpy(&u, &h, 4);
    return u;
}

// ---------------------------------------------------------------------------
// prep: build all bf16-transposed weights + folded graph biases.
// ---------------------------------------------------------------------------
__global__ void prep_kernel(const float* __restrict__ m1_w, const float* __restrict__ m2_w,
                            const float* __restrict__ o1_w, const float* __restrict__ t1_w,
                            const float* __restrict__ t2_w,
                            const float* __restrict__ me_w, const float* __restrict__ mlp1_w,
                            const float* __restrict__ mlp2_w,
                            const float* __restrict__ te1_w, const float* __restrict__ te2_w,
                            const float* __restrict__ te3_w,
                            const float* __restrict__ graph_fts,
                            const float* __restrict__ mg_w, const float* __restrict__ mg_b,
                            const float* __restrict__ m1_b,
                            const float* __restrict__ tg_w, const float* __restrict__ t2_b,
                            const float* __restrict__ tg_b,
                            ushort_t* __restrict__ Wnt,
                            ushort_t* __restrict__ Wme, ushort_t* __restrict__ Wm1,
                            ushort_t* __restrict__ Wm2, ushort_t* __restrict__ TEt,
                            float* __restrict__ G1, float* __restrict__ TG) {
    int idx = blockIdx.x * 256 + threadIdx.x;
    if (idx < 106496) {                       // Wnt: o*256 + k
        int o = idx >> 8, k = idx & 255;
        float v = 0.0f;
        if (o < 128)       v = m1_w[k * 128 + o];
        else if (o < 256)  v = m2_w[k * 128 + (o - 128)];
        else if (o < 384)  v = o1_w[k * 128 + (o - 256)];
        else if (o < 392)  v = t1_w[k * 8 + (o - 384)];
        else if (o < 400)  v = t2_w[k * 8 + (o - 392)];
        Wnt[idx] = f2b(v);
    } else if (idx < 122880) {
        int t = idx - 106496, o = t >> 7, h = t & 127;
        Wme[t] = f2b(me_w[h * 128 + o]);
    } else if (idx < 139264) {
        int t = idx - 122880, o = t >> 7, h = t & 127;
        Wm1[t] = f2b(mlp1_w[h * 128 + o]);
    } else if (idx < 155648) {
        int t = idx - 139264, o = t >> 7, h = t & 127;
        Wm2[t] = f2b(mlp2_w[h * 128 + o]);
    } else if (idx < 159744) {
        int t = idx - 155648, c = t >> 7, h = t & 127;
        float v = 0.0f;
        if (c < 8)       v = te1_w[h * 8 + c];
        else if (c < 16) v = te2_w[h * 8 + (c - 8)];
        else if (c < 24) v = te3_w[h * 8 + (c - 16)];
        TEt[t] = f2b(v);
    } else if (idx < 160256) {                // G1
        int t = idx - 159744, b = t >> 7, h = t & 127;
        float a = m1_b[h] + mg_b[h];
        #pragma unroll 4
        for (int k = 0; k < 128; k++) a = fmaf(graph_fts[b * 128 + k], mg_w[k * 128 + h], a);
        G1[t] = a;
    } else if (idx < 160288) {                // TG
        int t = idx - 160256, b = t >> 3, tt = t & 7;
        float a = t2_b[tt] + tg_b[tt];
        #pragma unroll 4
        for (int k = 0; k < 128; k++) a = fmaf(graph_fts[b * 128 + k], tg_w[k * 8 + tt], a);
        TG[t] = a;
    }
}

// ---------------------------------------------------------------------------
// node GEMM (MFMA bf16): Z[512x256] @ Wnt^T -> {M1,M2,O1z,T1v,TT2}
// ---------------------------------------------------------------------------
__global__ __launch_bounds__(256)
void node_gemm(const float* __restrict__ node_fts, const float* __restrict__ hidden,
               const ushort_t* __restrict__ Wnt,
               const float* __restrict__ G1, const float* __restrict__ m2_b,
               const float* __restrict__ o1_b, const float* __restrict__ t1_b,
               const float* __restrict__ TG,
               float* __restrict__ M1, float* __restrict__ M2, float* __restrict__ O1z,
               float* __restrict__ T1v, float* __restrict__ TT2) {
    __shared__ ushort_t Zs[32 * 256];         // 16 KB, swizzled
    char* Zb = (char*)Zs;
    const int tid = threadIdx.x;
    const int blk = blockIdx.x;               // 16 blocks
    const int b = blk >> 2, q = blk & 3;
    const int row0 = b * 128 + q * 32;
    const int w = tid >> 6, l = tid & 63, g = l >> 4, lq = l & 15;

    const float4* nsrc = reinterpret_cast<const float4*>(node_fts + (size_t)row0 * 128);
    const float4* hsrc = reinterpret_cast<const float4*>(hidden + (size_t)row0 * 128);
    #pragma unroll
    for (int p = 0; p < 8; p++) {
        int idx = tid + p * 256;
        int r = idx >> 6, c4 = idx & 63;
        float4 v = (c4 < 32) ? nsrc[r * 32 + c4] : hsrc[r * 32 + (c4 - 32)];
        uint2 pk;
        pk.x = pk2(v.x, v.y);
        pk.y = pk2(v.z, v.w);
        *reinterpret_cast<uint2*>(Zb + r * 512 + (((c4 >> 1) ^ (r & 7)) << 4) + (c4 & 1) * 8) = pk;
    }
    __syncthreads();

    for (int mt = w; mt < 26; mt += 4) {
        f32x4 acc0 = (f32x4){0.f, 0.f, 0.f, 0.f};
        f32x4 acc1 = (f32x4){0.f, 0.f, 0.f, 0.f};
        const ushort_t* arow = Wnt + (size_t)(mt * 16 + lq) * 256;
        #pragma unroll
        for (int ks = 0; ks < 8; ks++) {
            bf16x8 a = *reinterpret_cast<const bf16x8*>(arow + ks * 32 + g * 8);
            int j0 = lq, j1 = 16 + lq;
            bf16x8 b0 = *reinterpret_cast<const bf16x8*>(Zb + j0 * 512 + (((ks * 4 + g) ^ (j0 & 7)) << 4));
            bf16x8 b1 = *reinterpret_cast<const bf16x8*>(Zb + j1 * 512 + (((ks * 4 + g) ^ (j1 & 7)) << 4));
            acc0 = __builtin_amdgcn_mfma_f32_16x16x32_bf16(a, b0, acc0, 0, 0, 0);
            acc1 = __builtin_amdgcn_mfma_f32_16x16x32_bf16(a, b1, acc1, 0, 0, 0);
        }
        #pragma unroll
        for (int half = 0; half < 2; half++) {
            const f32x4 acc = half ? acc1 : acc0;
            const int grow = row0 + half * 16 + lq;
            #pragma unroll
            for (int c = 0; c < 4; c++) {
                int o = mt * 16 + g * 4 + c;
                float v = acc[c];
                if (o < 128)       M1[(size_t)grow * 128 + o] = v + G1[b * 128 + o];
                else if (o < 256)  M2[(size_t)grow * 128 + (o - 128)] = v + m2_b[o - 128];
                else if (o < 384)  O1z[(size_t)grow * 128 + (o - 256)] = v + o1_b[o - 256];
                else if (o < 392)  T1v[(size_t)grow * 8 + (o - 384)] = v + t1_b[o - 384];
                else if (o < 400)  TT2[(size_t)grow * 8 + (o - 392)] = v + TG[b * 8 + (o - 392)];
            }
        }
    }
}

// ---------------------------------------------------------------------------
// edge kernel, MFMA bf16. 512 blocks = (b, ie); 512 threads = 8 waves.
// Full 128x128 tile, ping-pong double-buffered LDS X (2 x 32 KB) -> 4 barriers.
// Wave w: o_blk = (w&3)*32 (2 m-frags), j_blk = (w>>2)*64 (4 n-frags).
// ---------------------------------------------------------------------------
__device__ __forceinline__ void mmv(const ushort_t* __restrict__ Wt, const char* Xa,
                                    f32x4 acc[2][4], int o_blk, int j_blk, int g, int lq) {
    #pragma unroll
    for (int ks = 0; ks < 4; ks++) {
        bf16x8 a[2], bb[4];
        #pragma unroll
        for (int m = 0; m < 2; m++)
            a[m] = *reinterpret_cast<const bf16x8*>(Wt + (size_t)(o_blk + m * 16 + lq) * 128 + ks * 32 + g * 8);
        #pragma unroll
        for (int n = 0; n < 4; n++) {
            int j = j_blk + n * 16 + lq;
            bb[n] = *reinterpret_cast<const bf16x8*>(Xa + j * 256 + (((ks * 4 + g) ^ (j & 7)) << 4));
        }
        #pragma unroll
        for (int m = 0; m < 2; m++)
            #pragma unroll
            for (int n = 0; n < 4; n++)
                acc[m][n] = __builtin_amdgcn_mfma_f32_16x16x32_bf16(a[m], bb[n], acc[m][n], 0, 0, 0);
    }
}

__global__ __launch_bounds__(512, 4)
void edge_kernel(const float* __restrict__ edge_fts,
                 const ushort_t* __restrict__ Wme, const float* __restrict__ me_b,
                 const ushort_t* __restrict__ Wm1, const float* __restrict__ mlp1_b,
                 const ushort_t* __restrict__ Wm2, const float* __restrict__ mlp2_b,
                 const ushort_t* __restrict__ TEt,
                 const float* __restrict__ te1_b, const float* __restrict__ te2_b,
                 const float* __restrict__ te3_b,
                 const float* __restrict__ M1,  const float* __restrict__ M2,
                 const float* __restrict__ T1v, const float* __restrict__ TT2,
                 ushort_t* __restrict__ msgsM, float* __restrict__ T1buf,
                 float* __restrict__ T2buf, float* __restrict__ E3buf) {
    __shared__ ushort_t Xs[2][16384];   // 2 x 32 KB bf16 tiles, swizzled
    char* X0 = (char*)Xs[0];
    char* X1 = (char*)Xs[1];
    const int tid = threadIdx.x;
    const int b  = blockIdx.x >> 7;
    const int ie = blockIdx.x & 127;
    const int w = tid >> 6, l = tid & 63, g = l >> 4, lq = l & 15;
    const int o_blk = (w & 3) * 32, j_blk = (w >> 2) * 64;

    // ---- stage 0: global fp32 -> bf16 swizzled LDS X0 (128 rows) ----
    const float4* esrc = reinterpret_cast<const float4*>(edge_fts + (size_t)(b * 128 + ie) * 16384);
    #pragma unroll
    for (int p = 0; p < 8; p++) {
        int idx = tid + p * 512;           // float4 index 0..4095
        int r = idx >> 5, c4 = idx & 31;
        float4 v = esrc[idx];
        uint2 pk;
        pk.x = pk2(v.x, v.y);
        pk.y = pk2(v.z, v.w);
        *reinterpret_cast<uint2*>(X0 + r * 256 + (((c4 >> 1) ^ (r & 7)) << 4) + (c4 & 1) * 8) = pk;
    }
    __syncthreads();                       // barrier 1

    // ---- te projections (read X0; write global; no extra barrier) ----
    {
        const int m_te = w & 1;
        const int jq = (w >> 1) & 3;       // j strip: jq*32 + n2*16
        const ushort_t* At = TEt + m_te * 16 * 128;
        f32x4 acc2[2];
        #pragma unroll
        for (int n = 0; n < 2; n++) acc2[n] = (f32x4){0.f, 0.f, 0.f, 0.f};
        #pragma unroll
        for (int ks = 0; ks < 4; ks++) {
            bf16x8 a = *reinterpret_cast<const bf16x8*>(At + lq * 128 + ks * 32 + g * 8);
            #pragma unroll
            for (int n = 0; n < 2; n++) {
                int j = jq * 32 + n * 16 + lq;
                bf16x8 bbv = *reinterpret_cast<const bf16x8*>(X0 + j * 256 + (((ks * 4 + g) ^ (j & 7)) << 4));
                acc2[n] = __builtin_amdgcn_mfma_f32_16x16x32_bf16(a, bbv, acc2[n], 0, 0, 0);
            }
        }
        if (m_te == 0) {
            if (g < 2) {   // te1: T1buf[b][j][ie][t] (+T1v[b,ie])
                int t0 = g * 4;
                const float4 eb = *reinterpret_cast<const float4*>(te1_b + t0);
                const float4 tv = *reinterpret_cast<const float4*>(T1v + (size_t)(b * 128 + ie) * 8 + t0);
                #pragma unroll
                for (int n = 0; n < 2; n++) {
                    int j = jq * 32 + n * 16 + lq;
                    float4 o4 = make_float4(acc2[n][0] + eb.x + tv.x, acc2[n][1] + eb.y + tv.y,
                                            acc2[n][2] + eb.z + tv.z, acc2[n][3] + eb.w + tv.w);
                    *reinterpret_cast<float4*>(T1buf + ((size_t)(b * 128 + j) * 128 + ie) * 8 + t0) = o4;
                }
            } else {       // te2: T2buf[b][ie][j][t]
                int t0 = g * 4 - 8;
                const float4 eb = *reinterpret_cast<const float4*>(te2_b + t0);
                #pragma unroll
                for (int n = 0; n < 2; n++) {
                    int j = jq * 32 + n * 16 + lq;
                    float4 o4 = make_float4(acc2[n][0] + eb.x, acc2[n][1] + eb.y,
                                            acc2[n][2] + eb.z, acc2[n][3] + eb.w);
                    *reinterpret_cast<float4*>(T2buf + ((size_t)(b * 128 + ie) * 128 + j) * 8 + t0) = o4;
                }
            }
        } else if (g < 2) { // te3: E3buf[b][ie][j][t] + TT2[b,ie] + T1v[b,j]
            int t0 = g * 4;
            const float4 eb = *reinterpret_cast<const float4*>(te3_b + t0);
            const float4 t2v = *reinterpret_cast<const float4*>(TT2 + (size_t)(b * 128 + ie) * 8 + t0);
            #pragma unroll
            for (int n = 0; n < 2; n++) {
                int j = jq * 32 + n * 16 + lq;
                const float4 t3v = *reinterpret_cast<const float4*>(T1v + (size_t)(b * 128 + j) * 8 + t0);
                float4 o4 = make_float4(acc2[n][0] + eb.x + t2v.x + t3v.x,
                                        acc2[n][1] + eb.y + t2v.y + t3v.y,
                                        acc2[n][2] + eb.z + t2v.z + t3v.z,
                                        acc2[n][3] + eb.w + t2v.w + t3v.w);
                *reinterpret_cast<float4*>(E3buf + ((size_t)(b * 128 + ie) * 128 + j) * 8 + t0) = o4;
            }
        }
    }

    f32x4 acc[2][4];

    // ================= stage 1: X1 = relu(X0@me_w + me_b + M1[b,j] + M2[b,ie]) =================
    #pragma unroll
    for (int m = 0; m < 2; m++)
        #pragma unroll
        for (int n = 0; n < 4; n++) acc[m][n] = (f32x4){0.f, 0.f, 0.f, 0.f};
    mmv(Wme, X0, acc, o_blk, j_blk, g, lq);
    {
        #pragma unroll
        for (int m = 0; m < 2; m++) {
            int o0 = o_blk + m * 16 + g * 4;
            const float4 eb = *reinterpret_cast<const float4*>(me_b + o0);
            const float4 m2 = *reinterpret_cast<const float4*>(M2 + (size_t)(b * 128 + ie) * 128 + o0);
            float4 bc = make_float4(eb.x + m2.x, eb.y + m2.y, eb.z + m2.z, eb.w + m2.w);
            #pragma unroll
            for (int n = 0; n < 4; n++) {
                int j = j_blk + n * 16 + lq;
                const float4 m1 = *reinterpret_cast<const float4*>(M1 + (size_t)(b * 128 + j) * 128 + o0);
                float r0 = fmaxf(acc[m][n][0] + bc.x + m1.x, 0.f);
                float r1 = fmaxf(acc[m][n][1] + bc.y + m1.y, 0.f);
                float r2 = fmaxf(acc[m][n][2] + bc.z + m1.z, 0.f);
                float r3 = fmaxf(acc[m][n][3] + bc.w + m1.w, 0.f);
                uint2 pk;
                pk.x = pk2(r0, r1);
                pk.y = pk2(r2, r3);
                *reinterpret_cast<uint2*>(X1 + j * 256 + ((((o0 >> 3) ^ (j & 7))) << 4) + (o0 & 7) * 2) = pk;
            }
        }
        __syncthreads();                   // barrier 2
    }

    // ================= stage 2: X0 = relu(X1@mlp1_w + mlp1_b) =================
    #pragma unroll
    for (int m = 0; m < 2; m++)
        #pragma unroll
        for (int n = 0; n < 4; n++) acc[m][n] = (f32x4){0.f, 0.f, 0.f, 0.f};
    mmv(Wm1, X1, acc, o_blk, j_blk, g, lq);
    {
        #pragma unroll
        for (int m = 0; m < 2; m++) {
            int o0 = o_blk + m * 16 + g * 4;
            const float4 bb = *reinterpret_cast<const float4*>(mlp1_b + o0);
            #pragma unroll
            for (int n = 0; n < 4; n++) {
                int j = j_blk + n * 16 + lq;
                float r0 = fmaxf(acc[m][n][0] + bb.x, 0.f);
                float r1 = fmaxf(acc[m][n][1] + bb.y, 0.f);
                float r2 = fmaxf(acc[m][n][2] + bb.z, 0.f);
                float r3 = fmaxf(acc[m][n][3] + bb.w, 0.f);
                uint2 pk;
                pk.x = pk2(r0, r1);
                pk.y = pk2(r2, r3);
                *reinterpret_cast<uint2*>(X0 + j * 256 + ((((o0 >> 3) ^ (j & 7))) << 4) + (o0 & 7) * 2) = pk;
            }
        }
        __syncthreads();                   // barrier 3
    }

    // ================= stage 3: X1 = X0@mlp2_w + mlp2_b (no relu) =================
    #pragma unroll
    for (int m = 0; m < 2; m++)
        #pragma unroll
        for (int n = 0; n < 4; n++) acc[m][n] = (f32x4){0.f, 0.f, 0.f, 0.f};
    mmv(Wm2, X0, acc, o_blk, j_blk, g, lq);
    {
        #pragma unroll
        for (int m = 0; m < 2; m++) {
            int o0 = o_blk + m * 16 + g * 4;
            const float4 bb = *reinterpret_cast<const float4*>(mlp2_b + o0);
            #pragma unroll
            for (int n = 0; n < 4; n++) {
                int j = j_blk + n * 16 + lq;
                float r0 = acc[m][n][0] + bb.x;
                float r1 = acc[m][n][1] + bb.y;
                float r2 = acc[m][n][2] + bb.z;
                float r3 = acc[m][n][3] + bb.w;
                uint2 pk;
                pk.x = pk2(r0, r1);
                pk.y = pk2(r2, r3);
                *reinterpret_cast<uint2*>(X1 + j * 256 + ((((o0 >> 3) ^ (j & 7))) << 4) + (o0 & 7) * 2) = pk;
            }
        }
        __syncthreads();                   // barrier 4
    }

    // ---- de-swizzle copy-out: msgsM[b][j=r][i=ie][h] bf16 ----
    {
        #pragma unroll
        for (int p = 0; p < 4; p++) {
            int idx = tid + p * 512;       // uint4 index 0..2047
            int r = idx >> 4, sc = idx & 15;
            uint4 v = *reinterpret_cast<const uint4*>(X1 + r * 256 + sc * 16);
            int logical = sc ^ (r & 7);
            *reinterpret_cast<uint4*>(msgsM + ((size_t)(b * 128 + r) * 128 + ie) * 128 + logical * 8) = v;
        }
    }
}

// ---------------------------------------------------------------------------
// masked max aggregation (msgsM[b][j][i][h] bf16, contiguous per (b,j)) + head
// ---------------------------------------------------------------------------
__global__ __launch_bounds__(256)
void agg_out_kernel(const ushort_t* __restrict__ msgsM, const int* __restrict__ adj,
                    const float* __restrict__ O1z,
                    const float* __restrict__ o2_w, const float* __restrict__ o2_b,
                    const float* __restrict__ scale, const float* __restrict__ bias,
                    float* __restrict__ out) {
    __shared__ float aggs[4][128];
    __shared__ float fagg[128];
    __shared__ float red[2][2];
    const int b = blockIdx.x >> 7, j = blockIdx.x & 127;
    const int t = threadIdx.x;
    const int wv = t >> 6, ln = t & 63;
    const ushort_t* msrc = msgsM + (size_t)(b * 128 + j) * 16384;
    const int* arow = adj + b * 16384 + j;
    float a0 = -1e9f, a1 = -1e9f;
    #pragma unroll 8
    for (int s = 0; s < 32; s++) {
        const int i = s * 4 + wv;
        uint32_t u = *reinterpret_cast<const uint32_t*>(msrc + i * 128 + ln * 2);
        bool m = (arow[i * 128] == 1);
        float x0 = b2f((ushort_t)(u & 0xffffu));
        float x1 = b2f((ushort_t)(u >> 16));
        a0 = m ? fmaxf(a0, x0) : a0;
        a1 = m ? fmaxf(a1, x1) : a1;
    }
    aggs[wv][ln * 2]     = a0;
    aggs[wv][ln * 2 + 1] = a1;
    __syncthreads();
    if (t < 128)
        fagg[t] = fmaxf(fmaxf(aggs[0][t], aggs[1][t]), fmaxf(aggs[2][t], aggs[3][t]));
    __syncthreads();

    float v = 0.0f;
    if (t < 128) {
        float val = o2_b[t] + O1z[(size_t)(b * 128 + j) * 128 + t];
        #pragma unroll 4
        for (int k = 0; k < 128; k++) val = fmaf(fagg[k], o2_w[k * 128 + t], val);
        v = fmaxf(val, 0.0f);
    }
    float s = v, s2 = v * v;
    #pragma unroll
    for (int off = 32; off >= 1; off >>= 1) {
        s += __shfl_down(s, off, 64);
        s2 += __shfl_down(s2, off, 64);
    }
    if (t < 128 && (t & 63) == 0) { red[t >> 6][0] = s; red[t >> 6][1] = s2; }
    __syncthreads();
    if (t < 128) {
        const float tot = red[0][0] + red[1][0];
        const float tot2 = red[0][1] + red[1][1];
        const float mean = tot * (1.0f / 128.0f);
        const float var = tot2 * (1.0f / 128.0f) - mean * mean;
        const float rstd = rsqrtf(var + 1e-5f);
        out[(size_t)(b * 128 + j) * 128 + t] = (v - mean) * rstd * scale[t] + bias[t];
    }
}

// ---------------------------------------------------------------------------
// triplet kernel: 1 jf per block, 512 threads (8 waves).
// ---------------------------------------------------------------------------
__global__ __launch_bounds__(512)
void tri_kernel(const float* __restrict__ T1buf, const float* __restrict__ T2buf,
                const float* __restrict__ E3buf, const float* __restrict__ o3_w,
                const float* __restrict__ o3_b, const float* __restrict__ scale,
                const float* __restrict__ bias, float* __restrict__ tri_out) {
    __shared__ __align__(16) float T1s[1024];
    __shared__ __align__(16) float E3s[1024];
    __shared__ __align__(16) float o3s[1024];
    __shared__ __align__(16) float Ps[4][128][8];
    const int b = blockIdx.x >> 7, jf = blockIdx.x & 127;
    const int tid = threadIdx.x;
    if (tid < 256) {
        reinterpret_cast<float4*>(T1s)[tid] =
            reinterpret_cast<const float4*>(T1buf + (size_t)(b * 128 + jf) * 1024)[tid];
        reinterpret_cast<float4*>(o3s)[tid] = reinterpret_cast<const float4*>(o3_w)[tid];
    } else {
        int t2 = tid - 256;
        reinterpret_cast<float4*>(E3s)[t2] =
            reinterpret_cast<const float4*>(E3buf + (size_t)(b * 128 + jf) * 1024)[t2];
    }
    __syncthreads();

    {
        const int kf = tid & 127, ih = tid >> 7;      // ih 0..3
        float a8[8];
        #pragma unroll
        for (int t = 0; t < 8; t++) a8[t] = -3.0e38f;
        const float4* t2p = reinterpret_cast<const float4*>(T2buf + (size_t)b * 131072);
        #pragma unroll 4
        for (int ii = 0; ii < 32; ++ii) {
            const int i = ih * 32 + ii;
            const float4 p = t2p[(i * 128 + kf) * 2];
            const float4 q = t2p[(i * 128 + kf) * 2 + 1];
            const float* t1r = &T1s[i * 8];
            a8[0] = fmaxf(a8[0], t1r[0] + p.x);
            a8[1] = fmaxf(a8[1], t1r[1] + p.y);
            a8[2] = fmaxf(a8[2], t1r[2] + p.z);
            a8[3] = fmaxf(a8[3], t1r[3] + p.w);
            a8[4] = fmaxf(a8[4], t1r[4] + q.x);
            a8[5] = fmaxf(a8[5], t1r[5] + q.y);
            a8[6] = fmaxf(a8[6], t1r[6] + q.z);
            a8[7] = fmaxf(a8[7], t1r[7] + q.w);
        }
        #pragma unroll
        for (int t = 0; t < 8; t++) Ps[ih][kf][t] = a8[t];
    }
    __syncthreads();

    const int w = tid >> 6, l = tid & 63;
    const float ob0 = o3_b[l],     ob1 = o3_b[l + 64];
    const float sc0 = scale[l],    sc1 = scale[l + 64];
    const float bi0 = bias[l],     bi1 = bias[l + 64];
    for (int kk = 0; kk < 16; ++kk) {
        const int kf = w * 16 + kk;
        float m8[8];
        #pragma unroll
        for (int t = 0; t < 8; t++)
            m8[t] = fmaxf(fmaxf(Ps[0][kf][t], Ps[1][kf][t]),
                          fmaxf(Ps[2][kf][t], Ps[3][kf][t])) + E3s[kf * 8 + t];
        float v0 = ob0, v1 = ob1;
        #pragma unroll
        for (int t = 0; t < 8; t++) {
            v0 = fmaf(m8[t], o3s[t * 128 + l], v0);
            v1 = fmaf(m8[t], o3s[t * 128 + l + 64], v1);
        }
        v0 = fmaxf(v0, 0.0f);
        v1 = fmaxf(v1, 0.0f);
        float s = v0 + v1, s2 = v0 * v0 + v1 * v1;
        #pragma unroll
        for (int off = 32; off >= 1; off >>= 1) {
            s  += __shfl_xor(s, off, 64);
            s2 += __shfl_xor(s2, off, 64);
        }
        const float mean = s * (1.0f / 128.0f);
        const float var = s2 * (1.0f / 128.0f) - mean * mean;
        const float rstd = rsqrtf(var + 1e-5f);
        float* dst = tri_out + (size_t)((b * 128 + jf) * 128 + kf) * 128;
        dst[l]      = (v0 - mean) * rstd * sc0 + bi0;
        dst[l + 64] = (v1 - mean) * rstd * sc1 + bi1;
    }
}

// ---------------------------------------------------------------------------
extern "C" void kernel_launch(void* const* d_in, const int* in_sizes, int n_in,
                              void* d_out, int out_size, void* d_ws, size_t ws_size,
                              hipStream_t stream) {
    const float* node_fts  = (const float*)d_in[0];
    const float* edge_fts  = (const float*)d_in[1];
    const float* graph_fts = (const float*)d_in[2];
    const float* hidden    = (const float*)d_in[3];
    const int*   adj       = (const int*)d_in[4];
    const float* m1_w = (const float*)d_in[5],  *m1_b = (const float*)d_in[6];
    const float* m2_w = (const float*)d_in[7],  *m2_b = (const float*)d_in[8];
    const float* me_w = (const float*)d_in[9],  *me_b = (const float*)d_in[10];
    const float* mg_w = (const float*)d_in[11], *mg_b = (const float*)d_in[12];
    const float* mlp1_w = (const float*)d_in[13], *mlp1_b = (const float*)d_in[14];
    const float* mlp2_w = (const float*)d_in[15], *mlp2_b = (const float*)d_in[16];
    const float* o1_w = (const float*)d_in[17], *o1_b = (const float*)d_in[18];
    const float* o2_w = (const float*)d_in[19], *o2_b = (const float*)d_in[20];
    const float* t1_w = (const float*)d_in[21], *t1_b = (const float*)d_in[22];
    const float* t2_w = (const float*)d_in[23], *t2_b = (const float*)d_in[24];
    const float* te1_w = (const float*)d_in[25], *te1_b = (const float*)d_in[26];
    const float* te2_w = (const float*)d_in[27], *te2_b = (const float*)d_in[28];
    const float* te3_w = (const float*)d_in[29], *te3_b = (const float*)d_in[30];
    const float* tg_w = (const float*)d_in[31], *tg_b = (const float*)d_in[32];
    const float* o3_w = (const float*)d_in[33], *o3_b = (const float*)d_in[34];
    const float* norm_scale = (const float*)d_in[35];
    const float* norm_bias  = (const float*)d_in[36];

    char* w8 = (char*)d_ws;
    float*    M1    = (float*)(w8 + 0);          // 256 KB
    float*    M2    = (float*)(w8 + 262144);     // 256 KB
    float*    O1z   = (float*)(w8 + 524288);     // 256 KB
    float*    T1v   = (float*)(w8 + 786432);     // 16 KB
    float*    TT2   = (float*)(w8 + 802816);     // 16 KB
    ushort_t* Wme   = (ushort_t*)(w8 + 819200);  // 32 KB
    ushort_t* Wm1   = (ushort_t*)(w8 + 851968);  // 32 KB
    ushort_t* Wm2   = (ushort_t*)(w8 + 884736);  // 32 KB
    ushort_t* TEt   = (ushort_t*)(w8 + 917504);  // 8 KB
    ushort_t* msgsM = (ushort_t*)(w8 + 925696);  // 16 MB
    float*    T1buf = (float*)(w8 + 17702912);   // 2 MB
    float*    T2buf = (float*)(w8 + 19800064);   // 2 MB
    float*    E3buf = (float*)(w8 + 21897216);   // 2 MB
    ushort_t* Wnt   = (ushort_t*)(w8 + 23994368);// 208 KB
    float*    G1    = (float*)(w8 + 24207360);   // 2 KB
    float*    TG    = (float*)(w8 + 24209408);   // 128 B

    float* out_p  = (float*)d_out;            // [4,128,128]
    float* tri_p  = (float*)d_out + 65536;    // [4,128,128,128]

    prep_kernel<<<627, 256, 0, stream>>>(m1_w, m2_w, o1_w, t1_w, t2_w,
                                         me_w, mlp1_w, mlp2_w, te1_w, te2_w, te3_w,
                                         graph_fts, mg_w, mg_b, m1_b, tg_w, t2_b, tg_b,
                                         Wnt, Wme, Wm1, Wm2, TEt, G1, TG);
    node_gemm<<<16, 256, 0, stream>>>(node_fts, hidden, Wnt, G1, m2_b, o1_b, t1_b, TG,
                                      M1, M2, O1z, T1v, TT2);
    edge_kernel<<<512, 512, 0, stream>>>(edge_fts, Wme, me_b, Wm1, mlp1_b, Wm2, mlp2_b,
                                         TEt, te1_b, te2_b, te3_b,
                                         M1, M2, T1v, TT2, msgsM, T1buf, T2buf, E3buf);
    agg_out_kernel<<<512, 256, 0, stream>>>(msgsM, adj, O1z, o2_w, o2_b,
                                            norm_scale, norm_bias, out_p);
    tri_kernel<<<512, 512, 0, stream>>>(T1buf, T2buf, E3buf, o3_w, o3_b,
                                        norm_scale, norm_bias, tri_p);
}

// Round 8
// 93.988 us; speedup vs baseline: 1.2755x; 1.1678x over previous
//
#include <hip/hip_runtime.h>
#include <hip/hip_bf16.h>
#include <cstddef>
#include <cstdint>
#include <cstring>

typedef __attribute__((ext_vector_type(8))) short bf16x8;
typedef __attribute__((ext_vector_type(4))) float f32x4;
typedef unsigned short ushort_t;

__device__ __forceinline__ ushort_t f2b(float f) {
    uint32_t x = __float_as_uint(f);
    uint32_t r = (x + 0x7FFFu + ((x >> 16) & 1u)) >> 16;   // RNE
    return (ushort_t)r;
}
__device__ __forceinline__ float b2f(ushort_t u) {
    return __uint_as_float(((uint32_t)u) << 16);
}
// packed 2xfp32 -> 2xbf16 via HW v_cvt_pk_bf16_f32
__device__ __forceinline__ uint32_t pk2(float x, float y) {
    __hip_bfloat162 h = __float22bfloat162_rn(float2{x, y});
    uint32_t u;
    __builtin_memcpy(&u, &h, 4);
    return u;
}

// ---------------------------------------------------------------------------
// prep: build all bf16-transposed weights + folded graph biases.
// ---------------------------------------------------------------------------
__global__ void prep_kernel(const float* __restrict__ m1_w, const float* __restrict__ m2_w,
                            const float* __restrict__ o1_w, const float* __restrict__ t1_w,
                            const float* __restrict__ t2_w,
                            const float* __restrict__ me_w, const float* __restrict__ mlp1_w,
                            const float* __restrict__ mlp2_w,
                            const float* __restrict__ te1_w, const float* __restrict__ te2_w,
                            const float* __restrict__ te3_w,
                            const float* __restrict__ graph_fts,
                            const float* __restrict__ mg_w, const float* __restrict__ mg_b,
                            const float* __restrict__ m1_b,
                            const float* __restrict__ tg_w, const float* __restrict__ t2_b,
                            const float* __restrict__ tg_b,
                            ushort_t* __restrict__ Wnt,
                            ushort_t* __restrict__ Wme, ushort_t* __restrict__ Wm1,
                            ushort_t* __restrict__ Wm2, ushort_t* __restrict__ TEt,
                            float* __restrict__ G1, float* __restrict__ TG) {
    int idx = blockIdx.x * 256 + threadIdx.x;
    if (idx < 106496) {                       // Wnt: o*256 + k
        int o = idx >> 8, k = idx & 255;
        float v = 0.0f;
        if (o < 128)       v = m1_w[k * 128 + o];
        else if (o < 256)  v = m2_w[k * 128 + (o - 128)];
        else if (o < 384)  v = o1_w[k * 128 + (o - 256)];
        else if (o < 392)  v = t1_w[k * 8 + (o - 384)];
        else if (o < 400)  v = t2_w[k * 8 + (o - 392)];
        Wnt[idx] = f2b(v);
    } else if (idx < 122880) {
        int t = idx - 106496, o = t >> 7, h = t & 127;
        Wme[t] = f2b(me_w[h * 128 + o]);
    } else if (idx < 139264) {
        int t = idx - 122880, o = t >> 7, h = t & 127;
        Wm1[t] = f2b(mlp1_w[h * 128 + o]);
    } else if (idx < 155648) {
        int t = idx - 139264, o = t >> 7, h = t & 127;
        Wm2[t] = f2b(mlp2_w[h * 128 + o]);
    } else if (idx < 159744) {
        int t = idx - 155648, c = t >> 7, h = t & 127;
        float v = 0.0f;
        if (c < 8)       v = te1_w[h * 8 + c];
        else if (c < 16) v = te2_w[h * 8 + (c - 8)];
        else if (c < 24) v = te3_w[h * 8 + (c - 16)];
        TEt[t] = f2b(v);
    } else if (idx < 160256) {                // G1
        int t = idx - 159744, b = t >> 7, h = t & 127;
        float a = m1_b[h] + mg_b[h];
        #pragma unroll 4
        for (int k = 0; k < 128; k++) a = fmaf(graph_fts[b * 128 + k], mg_w[k * 128 + h], a);
        G1[t] = a;
    } else if (idx < 160288) {                // TG
        int t = idx - 160256, b = t >> 3, tt = t & 7;
        float a = t2_b[tt] + tg_b[tt];
        #pragma unroll 4
        for (int k = 0; k < 128; k++) a = fmaf(graph_fts[b * 128 + k], tg_w[k * 8 + tt], a);
        TG[t] = a;
    }
}

// ---------------------------------------------------------------------------
// node GEMM (MFMA bf16): Z[512x256] @ Wnt^T -> {M1,M2,O1z,T1v,TT2}
// 32 blocks: 16 row tiles x 2 column halves (13 col-tiles each).
// ---------------------------------------------------------------------------
__global__ __launch_bounds__(256)
void node_gemm(const float* __restrict__ node_fts, const float* __restrict__ hidden,
               const ushort_t* __restrict__ Wnt,
               const float* __restrict__ G1, const float* __restrict__ m2_b,
               const float* __restrict__ o1_b, const float* __restrict__ t1_b,
               const float* __restrict__ TG,
               float* __restrict__ M1, float* __restrict__ M2, float* __restrict__ O1z,
               float* __restrict__ T1v, float* __restrict__ TT2) {
    __shared__ ushort_t Zs[32 * 256];         // 16 KB, swizzled
    char* Zb = (char*)Zs;
    const int tid = threadIdx.x;
    const int blk = blockIdx.x;               // 32 blocks
    const int rowblk = blk >> 1, colh = blk & 1;
    const int b = rowblk >> 2, q = rowblk & 3;
    const int row0 = b * 128 + q * 32;
    const int w = tid >> 6, l = tid & 63, g = l >> 4, lq = l & 15;

    const float4* nsrc = reinterpret_cast<const float4*>(node_fts + (size_t)row0 * 128);
    const float4* hsrc = reinterpret_cast<const float4*>(hidden + (size_t)row0 * 128);
    #pragma unroll
    for (int p = 0; p < 8; p++) {
        int idx = tid + p * 256;
        int r = idx >> 6, c4 = idx & 63;
        float4 v = (c4 < 32) ? nsrc[r * 32 + c4] : hsrc[r * 32 + (c4 - 32)];
        uint2 pk;
        pk.x = pk2(v.x, v.y);
        pk.y = pk2(v.z, v.w);
        *reinterpret_cast<uint2*>(Zb + r * 512 + (((c4 >> 1) ^ (r & 7)) << 4) + (c4 & 1) * 8) = pk;
    }
    __syncthreads();

    for (int mt = colh * 13 + w; mt < colh * 13 + 13; mt += 4) {
        f32x4 acc0 = (f32x4){0.f, 0.f, 0.f, 0.f};
        f32x4 acc1 = (f32x4){0.f, 0.f, 0.f, 0.f};
        const ushort_t* arow = Wnt + (size_t)(mt * 16 + lq) * 256;
        #pragma unroll
        for (int ks = 0; ks < 8; ks++) {
            bf16x8 a = *reinterpret_cast<const bf16x8*>(arow + ks * 32 + g * 8);
            int j0 = lq, j1 = 16 + lq;
            bf16x8 b0 = *reinterpret_cast<const bf16x8*>(Zb + j0 * 512 + (((ks * 4 + g) ^ (j0 & 7)) << 4));
            bf16x8 b1 = *reinterpret_cast<const bf16x8*>(Zb + j1 * 512 + (((ks * 4 + g) ^ (j1 & 7)) << 4));
            acc0 = __builtin_amdgcn_mfma_f32_16x16x32_bf16(a, b0, acc0, 0, 0, 0);
            acc1 = __builtin_amdgcn_mfma_f32_16x16x32_bf16(a, b1, acc1, 0, 0, 0);
        }
        #pragma unroll
        for (int half = 0; half < 2; half++) {
            const f32x4 acc = half ? acc1 : acc0;
            const int grow = row0 + half * 16 + lq;
            #pragma unroll
            for (int c = 0; c < 4; c++) {
                int o = mt * 16 + g * 4 + c;
                float v = acc[c];
                if (o < 128)       M1[(size_t)grow * 128 + o] = v + G1[b * 128 + o];
                else if (o < 256)  M2[(size_t)grow * 128 + (o - 128)] = v + m2_b[o - 128];
                else if (o < 384)  O1z[(size_t)grow * 128 + (o - 256)] = v + o1_b[o - 256];
                else if (o < 392)  T1v[(size_t)grow * 8 + (o - 384)] = v + t1_b[o - 384];
                else if (o < 400)  TT2[(size_t)grow * 8 + (o - 392)] = v + TG[b * 8 + (o - 392)];
            }
        }
    }
}

// ---------------------------------------------------------------------------
// edge kernel, MFMA bf16, j-major: block (b, jf), rows r = i.
// Tile X[r][h] = edge_fts[b, r, jf, :]. After the 3-stage MLP chain the block
// holds msgs[b, i=r, jf, :] in LDS -> fused masked-max over i + o2 head + LN
// writes out[b,jf,:] directly (no msgs materialization).
// ---------------------------------------------------------------------------
__device__ __forceinline__ void mmv(const ushort_t* __restrict__ Wt, const char* Xa,
                                    f32x4 acc[2][4], int o_blk, int j_blk, int g, int lq) {
    #pragma unroll
    for (int ks = 0; ks < 4; ks++) {
        bf16x8 a[2], bb[4];
        #pragma unroll
        for (int m = 0; m < 2; m++)
            a[m] = *reinterpret_cast<const bf16x8*>(Wt + (size_t)(o_blk + m * 16 + lq) * 128 + ks * 32 + g * 8);
        #pragma unroll
        for (int n = 0; n < 4; n++) {
            int j = j_blk + n * 16 + lq;
            bb[n] = *reinterpret_cast<const bf16x8*>(Xa + j * 256 + (((ks * 4 + g) ^ (j & 7)) << 4));
        }
        #pragma unroll
        for (int m = 0; m < 2; m++)
            #pragma unroll
            for (int n = 0; n < 4; n++)
                acc[m][n] = __builtin_amdgcn_mfma_f32_16x16x32_bf16(a[m], bb[n], acc[m][n], 0, 0, 0);
    }
}

__global__ __launch_bounds__(512, 4)
void edge_kernel(const float* __restrict__ edge_fts,
                 const ushort_t* __restrict__ Wme, const float* __restrict__ me_b,
                 const ushort_t* __restrict__ Wm1, const float* __restrict__ mlp1_b,
                 const ushort_t* __restrict__ Wm2, const float* __restrict__ mlp2_b,
                 const ushort_t* __restrict__ TEt,
                 const float* __restrict__ te1_b, const float* __restrict__ te2_b,
                 const float* __restrict__ te3_b,
                 const float* __restrict__ M1,  const float* __restrict__ M2,
                 const float* __restrict__ T1v, const float* __restrict__ TT2,
                 const int* __restrict__ adj, const float* __restrict__ O1z,
                 const float* __restrict__ o2_w, const float* __restrict__ o2_b,
                 const float* __restrict__ nsc, const float* __restrict__ nbi,
                 float* __restrict__ out,
                 float* __restrict__ T1buf, float* __restrict__ T2buf,
                 float* __restrict__ E3buf) {
    __shared__ ushort_t Xs[2][16384];   // 2 x 32 KB bf16 tiles, swizzled
    char* X0 = (char*)Xs[0];
    char* X1 = (char*)Xs[1];
    const int tid = threadIdx.x;
    const int b  = blockIdx.x >> 7;
    const int jf = blockIdx.x & 127;    // fixed output column j; rows r = i
    const int w = tid >> 6, l = tid & 63, g = l >> 4, lq = l & 15;
    const int o_blk = (w & 3) * 32, j_blk = (w >> 2) * 64;

    // ---- stage 0: load edge_fts[b, r, jf, :] (512B rows) -> bf16 swizzled X0 ----
    #pragma unroll
    for (int p = 0; p < 8; p++) {
        int idx = tid + p * 512;           // float4 index 0..4095
        int r = idx >> 5, c4 = idx & 31;
        const float4* src = reinterpret_cast<const float4*>(
            edge_fts + ((size_t)(b * 128 + r) * 128 + jf) * 128);
        float4 v = src[c4];
        uint2 pk;
        pk.x = pk2(v.x, v.y);
        pk.y = pk2(v.z, v.w);
        *reinterpret_cast<uint2*>(X0 + r * 256 + (((c4 >> 1) ^ (r & 7)) << 4) + (c4 & 1) * 8) = pk;
    }
    __syncthreads();                       // barrier 1

    // ---- te projections (read X0; write global; no extra barrier) ----
    // row r of X = edge_fts[b, i=r, j=jf]:
    //   te1 -> tri_e_1[b,r,jf] (+tri_1[b,r])       -> T1buf[b][jf][r]  (contiguous)
    //   te2 -> tri_e_2[b,r,jf]                      -> T2buf[b][r][jf]
    //   te3 -> tri_e_3[b,j=r,k=jf] (+TT2[b,r]+T1v[b,jf]) -> E3buf[b][r][jf]
    {
        const int m_te = w & 1;
        const int jq = (w >> 1) & 3;       // row strip: jq*32 + n*16
        const ushort_t* At = TEt + m_te * 16 * 128;
        f32x4 acc2[2];
        #pragma unroll
        for (int n = 0; n < 2; n++) acc2[n] = (f32x4){0.f, 0.f, 0.f, 0.f};
        #pragma unroll
        for (int ks = 0; ks < 4; ks++) {
            bf16x8 a = *reinterpret_cast<const bf16x8*>(At + lq * 128 + ks * 32 + g * 8);
            #pragma unroll
            for (int n = 0; n < 2; n++) {
                int j = jq * 32 + n * 16 + lq;
                bf16x8 bbv = *reinterpret_cast<const bf16x8*>(X0 + j * 256 + (((ks * 4 + g) ^ (j & 7)) << 4));
                acc2[n] = __builtin_amdgcn_mfma_f32_16x16x32_bf16(a, bbv, acc2[n], 0, 0, 0);
            }
        }
        if (m_te == 0) {
            if (g < 2) {   // te1
                int t0 = g * 4;
                const float4 eb = *reinterpret_cast<const float4*>(te1_b + t0);
                #pragma unroll
                for (int n = 0; n < 2; n++) {
                    int r = jq * 32 + n * 16 + lq;
                    const float4 tv = *reinterpret_cast<const float4*>(T1v + (size_t)(b * 128 + r) * 8 + t0);
                    float4 o4 = make_float4(acc2[n][0] + eb.x + tv.x, acc2[n][1] + eb.y + tv.y,
                                            acc2[n][2] + eb.z + tv.z, acc2[n][3] + eb.w + tv.w);
                    *reinterpret_cast<float4*>(T1buf + ((size_t)(b * 128 + jf) * 128 + r) * 8 + t0) = o4;
                }
            } else {       // te2
                int t0 = g * 4 - 8;
                const float4 eb = *reinterpret_cast<const float4*>(te2_b + t0);
                #pragma unroll
                for (int n = 0; n < 2; n++) {
                    int r = jq * 32 + n * 16 + lq;
                    float4 o4 = make_float4(acc2[n][0] + eb.x, acc2[n][1] + eb.y,
                                            acc2[n][2] + eb.z, acc2[n][3] + eb.w);
                    *reinterpret_cast<float4*>(T2buf + ((size_t)(b * 128 + r) * 128 + jf) * 8 + t0) = o4;
                }
            }
        } else if (g < 2) { // te3
            int t0 = g * 4;
            const float4 eb = *reinterpret_cast<const float4*>(te3_b + t0);
            const float4 t3v = *reinterpret_cast<const float4*>(T1v + (size_t)(b * 128 + jf) * 8 + t0);
            #pragma unroll
            for (int n = 0; n < 2; n++) {
                int r = jq * 32 + n * 16 + lq;
                const float4 t2v = *reinterpret_cast<const float4*>(TT2 + (size_t)(b * 128 + r) * 8 + t0);
                float4 o4 = make_float4(acc2[n][0] + eb.x + t2v.x + t3v.x,
                                        acc2[n][1] + eb.y + t2v.y + t3v.y,
                                        acc2[n][2] + eb.z + t2v.z + t3v.z,
                                        acc2[n][3] + eb.w + t2v.w + t3v.w);
                *reinterpret_cast<float4*>(E3buf + ((size_t)(b * 128 + r) * 128 + jf) * 8 + t0) = o4;
            }
        }
    }

    f32x4 acc[2][4];

    // ======= stage 1: X1 = relu(X0@me_w + me_b + M1[b,jf] + M2[b,i=r]) =======
    #pragma unroll
    for (int m = 0; m < 2; m++)
        #pragma unroll
        for (int n = 0; n < 4; n++) acc[m][n] = (f32x4){0.f, 0.f, 0.f, 0.f};
    mmv(Wme, X0, acc, o_blk, j_blk, g, lq);
    {
        #pragma unroll
        for (int m = 0; m < 2; m++) {
            int o0 = o_blk + m * 16 + g * 4;
            const float4 eb = *reinterpret_cast<const float4*>(me_b + o0);
            const float4 m1 = *reinterpret_cast<const float4*>(M1 + (size_t)(b * 128 + jf) * 128 + o0);
            float4 bc = make_float4(eb.x + m1.x, eb.y + m1.y, eb.z + m1.z, eb.w + m1.w);
            #pragma unroll
            for (int n = 0; n < 4; n++) {
                int j = j_blk + n * 16 + lq;       // row r = global i
                const float4 m2 = *reinterpret_cast<const float4*>(M2 + (size_t)(b * 128 + j) * 128 + o0);
                float r0 = fmaxf(acc[m][n][0] + bc.x + m2.x, 0.f);
                float r1 = fmaxf(acc[m][n][1] + bc.y + m2.y, 0.f);
                float r2 = fmaxf(acc[m][n][2] + bc.z + m2.z, 0.f);
                float r3 = fmaxf(acc[m][n][3] + bc.w + m2.w, 0.f);
                uint2 pk;
                pk.x = pk2(r0, r1);
                pk.y = pk2(r2, r3);
                *reinterpret_cast<uint2*>(X1 + j * 256 + ((((o0 >> 3) ^ (j & 7))) << 4) + (o0 & 7) * 2) = pk;
            }
        }
        __syncthreads();                   // barrier 2
    }

    // ======= stage 2: X0 = relu(X1@mlp1_w + mlp1_b) =======
    #pragma unroll
    for (int m = 0; m < 2; m++)
        #pragma unroll
        for (int n = 0; n < 4; n++) acc[m][n] = (f32x4){0.f, 0.f, 0.f, 0.f};
    mmv(Wm1, X1, acc, o_blk, j_blk, g, lq);
    {
        #pragma unroll
        for (int m = 0; m < 2; m++) {
            int o0 = o_blk + m * 16 + g * 4;
            const float4 bb = *reinterpret_cast<const float4*>(mlp1_b + o0);
            #pragma unroll
            for (int n = 0; n < 4; n++) {
                int j = j_blk + n * 16 + lq;
                float r0 = fmaxf(acc[m][n][0] + bb.x, 0.f);
                float r1 = fmaxf(acc[m][n][1] + bb.y, 0.f);
                float r2 = fmaxf(acc[m][n][2] + bb.z, 0.f);
                float r3 = fmaxf(acc[m][n][3] + bb.w, 0.f);
                uint2 pk;
                pk.x = pk2(r0, r1);
                pk.y = pk2(r2, r3);
                *reinterpret_cast<uint2*>(X0 + j * 256 + ((((o0 >> 3) ^ (j & 7))) << 4) + (o0 & 7) * 2) = pk;
            }
        }
        __syncthreads();                   // barrier 3
    }

    // ======= stage 3: X1 = X0@mlp2_w + mlp2_b (no relu) =======
    #pragma unroll
    for (int m = 0; m < 2; m++)
        #pragma unroll
        for (int n = 0; n < 4; n++) acc[m][n] = (f32x4){0.f, 0.f, 0.f, 0.f};
    mmv(Wm2, X0, acc, o_blk, j_blk, g, lq);
    {
        #pragma unroll
        for (int m = 0; m < 2; m++) {
            int o0 = o_blk + m * 16 + g * 4;
            const float4 bb = *reinterpret_cast<const float4*>(mlp2_b + o0);
            #pragma unroll
            for (int n = 0; n < 4; n++) {
                int j = j_blk + n * 16 + lq;
                float r0 = acc[m][n][0] + bb.x;
                float r1 = acc[m][n][1] + bb.y;
                float r2 = acc[m][n][2] + bb.z;
                float r3 = acc[m][n][3] + bb.w;
                uint2 pk;
                pk.x = pk2(r0, r1);
                pk.y = pk2(r2, r3);
                *reinterpret_cast<uint2*>(X1 + j * 256 + ((((o0 >> 3) ^ (j & 7))) << 4) + (o0 & 7) * 2) = pk;
            }
        }
        __syncthreads();                   // barrier 4 (also frees X0 for scratch)
    }

    // ======= fused epilogue: masked max over i + o2 head + LN -> out[b,jf,:] =======
    {
        float* scr  = reinterpret_cast<float*>(X0);   // X0 no longer needed
        float* aggs = scr;            // [4][128]
        float* fagg = scr + 512;      // [128]
        float* sums = scr + 640;      // [4][128]
        float* red  = scr + 1152;     // [4]
        const int h = tid & 127, wv = tid >> 7;
        {
            const int* acol = adj + b * 16384 + jf;
            float amax = -1e9f;
            #pragma unroll 8
            for (int s = 0; s < 32; s++) {
                int r = wv * 32 + s;
                ushort_t u = *reinterpret_cast<const ushort_t*>(
                    X1 + r * 256 + (((h >> 3) ^ (r & 7)) << 4) + (h & 7) * 2);
                amax = (acol[r * 128] == 1) ? fmaxf(amax, b2f(u)) : amax;
            }
            aggs[wv * 128 + h] = amax;
        }
        __syncthreads();
        if (tid < 128)
            fagg[tid] = fmaxf(fmaxf(aggs[tid], aggs[128 + tid]),
                              fmaxf(aggs[256 + tid], aggs[384 + tid]));
        __syncthreads();
        {
            float part = 0.f;
            const float* wcol = o2_w + h;
            #pragma unroll 8
            for (int k = wv * 32; k < wv * 32 + 32; k++)
                part = fmaf(fagg[k], wcol[k * 128], part);
            sums[wv * 128 + h] = part;
        }
        __syncthreads();
        float v = 0.f;
        if (tid < 128) {
            float val = o2_b[h] + O1z[(size_t)(b * 128 + jf) * 128 + h]
                      + sums[h] + sums[128 + h] + sums[256 + h] + sums[384 + h];
            v = fmaxf(val, 0.f);
        }
        float s = v, s2 = v * v;
        #pragma unroll
        for (int off = 32; off >= 1; off >>= 1) {
            s  += __shfl_down(s, off, 64);
            s2 += __shfl_down(s2, off, 64);
        }
        if (tid < 128 && (tid & 63) == 0) { red[tid >> 6] = s; red[2 + (tid >> 6)] = s2; }
        __syncthreads();
        if (tid < 128) {
            const float tot = red[0] + red[1], tot2 = red[2] + red[3];
            const float mean = tot * (1.0f / 128.0f);
            const float var = tot2 * (1.0f / 128.0f) - mean * mean;
            const float rstd = rsqrtf(var + 1e-5f);
            out[(size_t)(b * 128 + jf) * 128 + h] = (v - mean) * rstd * nsc[h] + nbi[h];
        }
    }
}

// ---------------------------------------------------------------------------
// triplet kernel: 1 jf per block, 512 threads (8 waves).
// ---------------------------------------------------------------------------
__global__ __launch_bounds__(512)
void tri_kernel(const float* __restrict__ T1buf, const float* __restrict__ T2buf,
                const float* __restrict__ E3buf, const float* __restrict__ o3_w,
                const float* __restrict__ o3_b, const float* __restrict__ scale,
                const float* __restrict__ bias, float* __restrict__ tri_out) {
    __shared__ __align__(16) float T1s[1024];
    __shared__ __align__(16) float E3s[1024];
    __shared__ __align__(16) float o3s[1024];
    __shared__ __align__(16) float Ps[4][128][8];
    const int b = blockIdx.x >> 7, jf = blockIdx.x & 127;
    const int tid = threadIdx.x;
    if (tid < 256) {
        reinterpret_cast<float4*>(T1s)[tid] =
            reinterpret_cast<const float4*>(T1buf + (size_t)(b * 128 + jf) * 1024)[tid];
        reinterpret_cast<float4*>(o3s)[tid] = reinterpret_cast<const float4*>(o3_w)[tid];
    } else {
        int t2 = tid - 256;
        reinterpret_cast<float4*>(E3s)[t2] =
            reinterpret_cast<const float4*>(E3buf + (size_t)(b * 128 + jf) * 1024)[t2];
    }
    __syncthreads();

    {
        const int kf = tid & 127, ih = tid >> 7;      // ih 0..3
        float a8[8];
        #pragma unroll
        for (int t = 0; t < 8; t++) a8[t] = -3.0e38f;
        const float4* t2p = reinterpret_cast<const float4*>(T2buf + (size_t)b * 131072);
        #pragma unroll 4
        for (int ii = 0; ii < 32; ++ii) {
            const int i = ih * 32 + ii;
            const float4 p = t2p[(i * 128 + kf) * 2];
            const float4 q = t2p[(i * 128 + kf) * 2 + 1];
            const float* t1r = &T1s[i * 8];
            a8[0] = fmaxf(a8[0], t1r[0] + p.x);
            a8[1] = fmaxf(a8[1], t1r[1] + p.y);
            a8[2] = fmaxf(a8[2], t1r[2] + p.z);
            a8[3] = fmaxf(a8[3], t1r[3] + p.w);
            a8[4] = fmaxf(a8[4], t1r[4] + q.x);
            a8[5] = fmaxf(a8[5], t1r[5] + q.y);
            a8[6] = fmaxf(a8[6], t1r[6] + q.z);
            a8[7] = fmaxf(a8[7], t1r[7] + q.w);
        }
        #pragma unroll
        for (int t = 0; t < 8; t++) Ps[ih][kf][t] = a8[t];
    }
    __syncthreads();

    const int w = tid >> 6, l = tid & 63;
    const float ob0 = o3_b[l],     ob1 = o3_b[l + 64];
    const float sc0 = scale[l],    sc1 = scale[l + 64];
    const float bi0 = bias[l],     bi1 = bias[l + 64];
    for (int kk = 0; kk < 16; ++kk) {
        const int kf = w * 16 + kk;
        float m8[8];
        #pragma unroll
        for (int t = 0; t < 8; t++)
            m8[t] = fmaxf(fmaxf(Ps[0][kf][t], Ps[1][kf][t]),
                          fmaxf(Ps[2][kf][t], Ps[3][kf][t])) + E3s[kf * 8 + t];
        float v0 = ob0, v1 = ob1;
        #pragma unroll
        for (int t = 0; t < 8; t++) {
            v0 = fmaf(m8[t], o3s[t * 128 + l], v0);
            v1 = fmaf(m8[t], o3s[t * 128 + l + 64], v1);
        }
        v0 = fmaxf(v0, 0.0f);
        v1 = fmaxf(v1, 0.0f);
        float s = v0 + v1, s2 = v0 * v0 + v1 * v1;
        #pragma unroll
        for (int off = 32; off >= 1; off >>= 1) {
            s  += __shfl_xor(s, off, 64);
            s2 += __shfl_xor(s2, off, 64);
        }
        const float mean = s * (1.0f / 128.0f);
        const float var = s2 * (1.0f / 128.0f) - mean * mean;
        const float rstd = rsqrtf(var + 1e-5f);
        float* dst = tri_out + (size_t)((b * 128 + jf) * 128 + kf) * 128;
        dst[l]      = (v0 - mean) * rstd * sc0 + bi0;
        dst[l + 64] = (v1 - mean) * rstd * sc1 + bi1;
    }
}

// ---------------------------------------------------------------------------
extern "C" void kernel_launch(void* const* d_in, const int* in_sizes, int n_in,
                              void* d_out, int out_size, void* d_ws, size_t ws_size,
                              hipStream_t stream) {
    const float* node_fts  = (const float*)d_in[0];
    const float* edge_fts  = (const float*)d_in[1];
    const float* graph_fts = (const float*)d_in[2];
    const float* hidden    = (const float*)d_in[3];
    const int*   adj       = (const int*)d_in[4];
    const float* m1_w = (const float*)d_in[5],  *m1_b = (const float*)d_in[6];
    const float* m2_w = (const float*)d_in[7],  *m2_b = (const float*)d_in[8];
    const float* me_w = (const float*)d_in[9],  *me_b = (const float*)d_in[10];
    const float* mg_w = (const float*)d_in[11], *mg_b = (const float*)d_in[12];
    const float* mlp1_w = (const float*)d_in[13], *mlp1_b = (const float*)d_in[14];
    const float* mlp2_w = (const float*)d_in[15], *mlp2_b = (const float*)d_in[16];
    const float* o1_w = (const float*)d_in[17], *o1_b = (const float*)d_in[18];
    const float* o2_w = (const float*)d_in[19], *o2_b = (const float*)d_in[20];
    const float* t1_w = (const float*)d_in[21], *t1_b = (const float*)d_in[22];
    const float* t2_w = (const float*)d_in[23], *t2_b = (const float*)d_in[24];
    const float* te1_w = (const float*)d_in[25], *te1_b = (const float*)d_in[26];
    const float* te2_w = (const float*)d_in[27], *te2_b = (const float*)d_in[28];
    const float* te3_w = (const float*)d_in[29], *te3_b = (const float*)d_in[30];
    const float* tg_w = (const float*)d_in[31], *tg_b = (const float*)d_in[32];
    const float* o3_w = (const float*)d_in[33], *o3_b = (const float*)d_in[34];
    const float* norm_scale = (const float*)d_in[35];
    const float* norm_bias  = (const float*)d_in[36];

    char* w8 = (char*)d_ws;
    float*    M1    = (float*)(w8 + 0);          // 256 KB
    float*    M2    = (float*)(w8 + 262144);     // 256 KB
    float*    O1z   = (float*)(w8 + 524288);     // 256 KB
    float*    T1v   = (float*)(w8 + 786432);     // 16 KB
    float*    TT2   = (float*)(w8 + 802816);     // 16 KB
    ushort_t* Wme   = (ushort_t*)(w8 + 819200);  // 32 KB
    ushort_t* Wm1   = (ushort_t*)(w8 + 851968);  // 32 KB
    ushort_t* Wm2   = (ushort_t*)(w8 + 884736);  // 32 KB
    ushort_t* TEt   = (ushort_t*)(w8 + 917504);  // 8 KB
    float*    T1buf = (float*)(w8 + 17702912);   // 2 MB
    float*    T2buf = (float*)(w8 + 19800064);   // 2 MB
    float*    E3buf = (float*)(w8 + 21897216);   // 2 MB
    ushort_t* Wnt   = (ushort_t*)(w8 + 23994368);// 208 KB
    float*    G1    = (float*)(w8 + 24207360);   // 2 KB
    float*    TG    = (float*)(w8 + 24209408);   // 128 B

    float* out_p  = (float*)d_out;            // [4,128,128]
    float* tri_p  = (float*)d_out + 65536;    // [4,128,128,128]

    prep_kernel<<<627, 256, 0, stream>>>(m1_w, m2_w, o1_w, t1_w, t2_w,
                                         me_w, mlp1_w, mlp2_w, te1_w, te2_w, te3_w,
                                         graph_fts, mg_w, mg_b, m1_b, tg_w, t2_b, tg_b,
                                         Wnt, Wme, Wm1, Wm2, TEt, G1, TG);
    node_gemm<<<32, 256, 0, stream>>>(node_fts, hidden, Wnt, G1, m2_b, o1_b, t1_b, TG,
                                      M1, M2, O1z, T1v, TT2);
    edge_kernel<<<512, 512, 0, stream>>>(edge_fts, Wme, me_b, Wm1, mlp1_b, Wm2, mlp2_b,
                                         TEt, te1_b, te2_b, te3_b,
                                         M1, M2, T1v, TT2,
                                         adj, O1z, o2_w, o2_b, norm_scale, norm_bias,
                                         out_p, T1buf, T2buf, E3buf);
    tri_kernel<<<512, 512, 0, stream>>>(T1buf, T2buf, E3buf, o3_w, o3_b,
                                        norm_scale, norm_bias, tri_p);
}

// Round 9
// 89.671 us; speedup vs baseline: 1.3369x; 1.0481x over previous
//
#include <hip/hip_runtime.h>
#include <hip/hip_bf16.h>
#include <cstddef>
#include <cstdint>
#include <cstring>

typedef __attribute__((ext_vector_type(8))) short bf16x8;
typedef __attribute__((ext_vector_type(4))) float f32x4;
typedef unsigned short ushort_t;

__device__ __forceinline__ ushort_t f2b(float f) {
    uint32_t x = __float_as_uint(f);
    uint32_t r = (x + 0x7FFFu + ((x >> 16) & 1u)) >> 16;   // RNE
    return (ushort_t)r;
}
__device__ __forceinline__ float b2f(ushort_t u) {
    return __uint_as_float(((uint32_t)u) << 16);
}
// packed 2xfp32 -> 2xbf16 via HW v_cvt_pk_bf16_f32
__device__ __forceinline__ uint32_t pk2(float x, float y) {
    __hip_bfloat162 h = __float22bfloat162_rn(float2{x, y});
    uint32_t u;
    __builtin_memcpy(&u, &h, 4);
    return u;
}

// ---------------------------------------------------------------------------
// prep: build all bf16-transposed weights + folded graph biases.
// ---------------------------------------------------------------------------
__global__ void prep_kernel(const float* __restrict__ m1_w, const float* __restrict__ m2_w,
                            const float* __restrict__ o1_w, const float* __restrict__ t1_w,
                            const float* __restrict__ t2_w,
                            const float* __restrict__ me_w, const float* __restrict__ mlp1_w,
                            const float* __restrict__ mlp2_w,
                            const float* __restrict__ te1_w, const float* __restrict__ te2_w,
                            const float* __restrict__ te3_w,
                            const float* __restrict__ graph_fts,
                            const float* __restrict__ mg_w, const float* __restrict__ mg_b,
                            const float* __restrict__ m1_b,
                            const float* __restrict__ tg_w, const float* __restrict__ t2_b,
                            const float* __restrict__ tg_b,
                            ushort_t* __restrict__ Wnt,
                            ushort_t* __restrict__ Wme, ushort_t* __restrict__ Wm1,
                            ushort_t* __restrict__ Wm2, ushort_t* __restrict__ TEt,
                            float* __restrict__ G1, float* __restrict__ TG) {
    int idx = blockIdx.x * 256 + threadIdx.x;
    if (idx < 106496) {                       // Wnt: o*256 + k
        int o = idx >> 8, k = idx & 255;
        float v = 0.0f;
        if (o < 128)       v = m1_w[k * 128 + o];
        else if (o < 256)  v = m2_w[k * 128 + (o - 128)];
        else if (o < 384)  v = o1_w[k * 128 + (o - 256)];
        else if (o < 392)  v = t1_w[k * 8 + (o - 384)];
        else if (o < 400)  v = t2_w[k * 8 + (o - 392)];
        Wnt[idx] = f2b(v);
    } else if (idx < 122880) {
        int t = idx - 106496, o = t >> 7, h = t & 127;
        Wme[t] = f2b(me_w[h * 128 + o]);
    } else if (idx < 139264) {
        int t = idx - 122880, o = t >> 7, h = t & 127;
        Wm1[t] = f2b(mlp1_w[h * 128 + o]);
    } else if (idx < 155648) {
        int t = idx - 139264, o = t >> 7, h = t & 127;
        Wm2[t] = f2b(mlp2_w[h * 128 + o]);
    } else if (idx < 159744) {
        int t = idx - 155648, c = t >> 7, h = t & 127;
        float v = 0.0f;
        if (c < 8)       v = te1_w[h * 8 + c];
        else if (c < 16) v = te2_w[h * 8 + (c - 8)];
        else if (c < 24) v = te3_w[h * 8 + (c - 16)];
        TEt[t] = f2b(v);
    } else if (idx < 160256) {                // G1
        int t = idx - 159744, b = t >> 7, h = t & 127;
        float a = m1_b[h] + mg_b[h];
        #pragma unroll 4
        for (int k = 0; k < 128; k++) a = fmaf(graph_fts[b * 128 + k], mg_w[k * 128 + h], a);
        G1[t] = a;
    } else if (idx < 160288) {                // TG
        int t = idx - 160256, b = t >> 3, tt = t & 7;
        float a = t2_b[tt] + tg_b[tt];
        #pragma unroll 4
        for (int k = 0; k < 128; k++) a = fmaf(graph_fts[b * 128 + k], tg_w[k * 8 + tt], a);
        TG[t] = a;
    }
}

// ---------------------------------------------------------------------------
// node GEMM (MFMA bf16): Z[512x256] @ Wnt^T -> {M1,M2,O1z,T1v,TT2}
// ---------------------------------------------------------------------------
__global__ __launch_bounds__(256)
void node_gemm(const float* __restrict__ node_fts, const float* __restrict__ hidden,
               const ushort_t* __restrict__ Wnt,
               const float* __restrict__ G1, const float* __restrict__ m2_b,
               const float* __restrict__ o1_b, const float* __restrict__ t1_b,
               const float* __restrict__ TG,
               float* __restrict__ M1, float* __restrict__ M2, float* __restrict__ O1z,
               float* __restrict__ T1v, float* __restrict__ TT2) {
    __shared__ ushort_t Zs[32 * 256];         // 16 KB, swizzled
    char* Zb = (char*)Zs;
    const int tid = threadIdx.x;
    const int blk = blockIdx.x;               // 32 blocks
    const int rowblk = blk >> 1, colh = blk & 1;
    const int b = rowblk >> 2, q = rowblk & 3;
    const int row0 = b * 128 + q * 32;
    const int w = tid >> 6, l = tid & 63, g = l >> 4, lq = l & 15;

    const float4* nsrc = reinterpret_cast<const float4*>(node_fts + (size_t)row0 * 128);
    const float4* hsrc = reinterpret_cast<const float4*>(hidden + (size_t)row0 * 128);
    #pragma unroll
    for (int p = 0; p < 8; p++) {
        int idx = tid + p * 256;
        int r = idx >> 6, c4 = idx & 63;
        float4 v = (c4 < 32) ? nsrc[r * 32 + c4] : hsrc[r * 32 + (c4 - 32)];
        uint2 pk;
        pk.x = pk2(v.x, v.y);
        pk.y = pk2(v.z, v.w);
        *reinterpret_cast<uint2*>(Zb + r * 512 + (((c4 >> 1) ^ (r & 7)) << 4) + (c4 & 1) * 8) = pk;
    }
    __syncthreads();

    for (int mt = colh * 13 + w; mt < colh * 13 + 13; mt += 4) {
        f32x4 acc0 = (f32x4){0.f, 0.f, 0.f, 0.f};
        f32x4 acc1 = (f32x4){0.f, 0.f, 0.f, 0.f};
        const ushort_t* arow = Wnt + (size_t)(mt * 16 + lq) * 256;
        #pragma unroll
        for (int ks = 0; ks < 8; ks++) {
            bf16x8 a = *reinterpret_cast<const bf16x8*>(arow + ks * 32 + g * 8);
            int j0 = lq, j1 = 16 + lq;
            bf16x8 b0 = *reinterpret_cast<const bf16x8*>(Zb + j0 * 512 + (((ks * 4 + g) ^ (j0 & 7)) << 4));
            bf16x8 b1 = *reinterpret_cast<const bf16x8*>(Zb + j1 * 512 + (((ks * 4 + g) ^ (j1 & 7)) << 4));
            acc0 = __builtin_amdgcn_mfma_f32_16x16x32_bf16(a, b0, acc0, 0, 0, 0);
            acc1 = __builtin_amdgcn_mfma_f32_16x16x32_bf16(a, b1, acc1, 0, 0, 0);
        }
        #pragma unroll
        for (int half = 0; half < 2; half++) {
            const f32x4 acc = half ? acc1 : acc0;
            const int grow = row0 + half * 16 + lq;
            #pragma unroll
            for (int c = 0; c < 4; c++) {
                int o = mt * 16 + g * 4 + c;
                float v = acc[c];
                if (o < 128)       M1[(size_t)grow * 128 + o] = v + G1[b * 128 + o];
                else if (o < 256)  M2[(size_t)grow * 128 + (o - 128)] = v + m2_b[o - 128];
                else if (o < 384)  O1z[(size_t)grow * 128 + (o - 256)] = v + o1_b[o - 256];
                else if (o < 392)  T1v[(size_t)grow * 8 + (o - 384)] = v + t1_b[o - 384];
                else if (o < 400)  TT2[(size_t)grow * 8 + (o - 392)] = v + TG[b * 8 + (o - 392)];
            }
        }
    }
}

// ---------------------------------------------------------------------------
// edge kernel, MFMA bf16, j-major, fused agg+head+LN epilogue.
// T1buf/T2buf/E3buf written as bf16.
// ---------------------------------------------------------------------------
__device__ __forceinline__ void mmv(const ushort_t* __restrict__ Wt, const char* Xa,
                                    f32x4 acc[2][4], int o_blk, int j_blk, int g, int lq) {
    #pragma unroll
    for (int ks = 0; ks < 4; ks++) {
        bf16x8 a[2], bb[4];
        #pragma unroll
        for (int m = 0; m < 2; m++)
            a[m] = *reinterpret_cast<const bf16x8*>(Wt + (size_t)(o_blk + m * 16 + lq) * 128 + ks * 32 + g * 8);
        #pragma unroll
        for (int n = 0; n < 4; n++) {
            int j = j_blk + n * 16 + lq;
            bb[n] = *reinterpret_cast<const bf16x8*>(Xa + j * 256 + (((ks * 4 + g) ^ (j & 7)) << 4));
        }
        #pragma unroll
        for (int m = 0; m < 2; m++)
            #pragma unroll
            for (int n = 0; n < 4; n++)
                acc[m][n] = __builtin_amdgcn_mfma_f32_16x16x32_bf16(a[m], bb[n], acc[m][n], 0, 0, 0);
    }
}

__global__ __launch_bounds__(512, 4)
void edge_kernel(const float* __restrict__ edge_fts,
                 const ushort_t* __restrict__ Wme, const float* __restrict__ me_b,
                 const ushort_t* __restrict__ Wm1, const float* __restrict__ mlp1_b,
                 const ushort_t* __restrict__ Wm2, const float* __restrict__ mlp2_b,
                 const ushort_t* __restrict__ TEt,
                 const float* __restrict__ te1_b, const float* __restrict__ te2_b,
                 const float* __restrict__ te3_b,
                 const float* __restrict__ M1,  const float* __restrict__ M2,
                 const float* __restrict__ T1v, const float* __restrict__ TT2,
                 const int* __restrict__ adj, const float* __restrict__ O1z,
                 const float* __restrict__ o2_w, const float* __restrict__ o2_b,
                 const float* __restrict__ nsc, const float* __restrict__ nbi,
                 float* __restrict__ out,
                 ushort_t* __restrict__ T1buf, ushort_t* __restrict__ T2buf,
                 ushort_t* __restrict__ E3buf) {
    __shared__ ushort_t Xs[2][16384];   // 2 x 32 KB bf16 tiles, swizzled
    char* X0 = (char*)Xs[0];
    char* X1 = (char*)Xs[1];
    const int tid = threadIdx.x;
    const int b  = blockIdx.x >> 7;
    const int jf = blockIdx.x & 127;    // fixed output column j; rows r = i
    const int w = tid >> 6, l = tid & 63, g = l >> 4, lq = l & 15;
    const int o_blk = (w & 3) * 32, j_blk = (w >> 2) * 64;

    // ---- stage 0: load edge_fts[b, r, jf, :] -> bf16 swizzled X0 ----
    #pragma unroll
    for (int p = 0; p < 8; p++) {
        int idx = tid + p * 512;           // float4 index 0..4095
        int r = idx >> 5, c4 = idx & 31;
        const float4* src = reinterpret_cast<const float4*>(
            edge_fts + ((size_t)(b * 128 + r) * 128 + jf) * 128);
        float4 v = src[c4];
        uint2 pk;
        pk.x = pk2(v.x, v.y);
        pk.y = pk2(v.z, v.w);
        *reinterpret_cast<uint2*>(X0 + r * 256 + (((c4 >> 1) ^ (r & 7)) << 4) + (c4 & 1) * 8) = pk;
    }
    __syncthreads();                       // barrier 1

    // ---- te projections (read X0; write global bf16) ----
    {
        const int m_te = w & 1;
        const int jq = (w >> 1) & 3;       // row strip: jq*32 + n*16
        const ushort_t* At = TEt + m_te * 16 * 128;
        f32x4 acc2[2];
        #pragma unroll
        for (int n = 0; n < 2; n++) acc2[n] = (f32x4){0.f, 0.f, 0.f, 0.f};
        #pragma unroll
        for (int ks = 0; ks < 4; ks++) {
            bf16x8 a = *reinterpret_cast<const bf16x8*>(At + lq * 128 + ks * 32 + g * 8);
            #pragma unroll
            for (int n = 0; n < 2; n++) {
                int j = jq * 32 + n * 16 + lq;
                bf16x8 bbv = *reinterpret_cast<const bf16x8*>(X0 + j * 256 + (((ks * 4 + g) ^ (j & 7)) << 4));
                acc2[n] = __builtin_amdgcn_mfma_f32_16x16x32_bf16(a, bbv, acc2[n], 0, 0, 0);
            }
        }
        if (m_te == 0) {
            if (g < 2) {   // te1 -> T1buf[b][jf][r][t] (+T1v[b,r]) bf16
                int t0 = g * 4;
                const float4 eb = *reinterpret_cast<const float4*>(te1_b + t0);
                #pragma unroll
                for (int n = 0; n < 2; n++) {
                    int r = jq * 32 + n * 16 + lq;
                    const float4 tv = *reinterpret_cast<const float4*>(T1v + (size_t)(b * 128 + r) * 8 + t0);
                    uint2 pkv;
                    pkv.x = pk2(acc2[n][0] + eb.x + tv.x, acc2[n][1] + eb.y + tv.y);
                    pkv.y = pk2(acc2[n][2] + eb.z + tv.z, acc2[n][3] + eb.w + tv.w);
                    *reinterpret_cast<uint2*>(T1buf + ((size_t)(b * 128 + jf) * 128 + r) * 8 + t0) = pkv;
                }
            } else {       // te2 -> T2buf[b][r][jf][t] bf16
                int t0 = g * 4 - 8;
                const float4 eb = *reinterpret_cast<const float4*>(te2_b + t0);
                #pragma unroll
                for (int n = 0; n < 2; n++) {
                    int r = jq * 32 + n * 16 + lq;
                    uint2 pkv;
                    pkv.x = pk2(acc2[n][0] + eb.x, acc2[n][1] + eb.y);
                    pkv.y = pk2(acc2[n][2] + eb.z, acc2[n][3] + eb.w);
                    *reinterpret_cast<uint2*>(T2buf + ((size_t)(b * 128 + r) * 128 + jf) * 8 + t0) = pkv;
                }
            }
        } else if (g < 2) { // te3 -> E3buf[b][r][jf][t] + TT2[b,r] + T1v[b,jf] bf16
            int t0 = g * 4;
            const float4 eb = *reinterpret_cast<const float4*>(te3_b + t0);
            const float4 t3v = *reinterpret_cast<const float4*>(T1v + (size_t)(b * 128 + jf) * 8 + t0);
            #pragma unroll
            for (int n = 0; n < 2; n++) {
                int r = jq * 32 + n * 16 + lq;
                const float4 t2v = *reinterpret_cast<const float4*>(TT2 + (size_t)(b * 128 + r) * 8 + t0);
                uint2 pkv;
                pkv.x = pk2(acc2[n][0] + eb.x + t2v.x + t3v.x, acc2[n][1] + eb.y + t2v.y + t3v.y);
                pkv.y = pk2(acc2[n][2] + eb.z + t2v.z + t3v.z, acc2[n][3] + eb.w + t2v.w + t3v.w);
                *reinterpret_cast<uint2*>(E3buf + ((size_t)(b * 128 + r) * 128 + jf) * 8 + t0) = pkv;
            }
        }
    }

    f32x4 acc[2][4];

    // ======= stage 1: X1 = relu(X0@me_w + me_b + M1[b,jf] + M2[b,i=r]) =======
    #pragma unroll
    for (int m = 0; m < 2; m++)
        #pragma unroll
        for (int n = 0; n < 4; n++) acc[m][n] = (f32x4){0.f, 0.f, 0.f, 0.f};
    mmv(Wme, X0, acc, o_blk, j_blk, g, lq);
    {
        #pragma unroll
        for (int m = 0; m < 2; m++) {
            int o0 = o_blk + m * 16 + g * 4;
            const float4 eb = *reinterpret_cast<const float4*>(me_b + o0);
            const float4 m1 = *reinterpret_cast<const float4*>(M1 + (size_t)(b * 128 + jf) * 128 + o0);
            float4 bc = make_float4(eb.x + m1.x, eb.y + m1.y, eb.z + m1.z, eb.w + m1.w);
            #pragma unroll
            for (int n = 0; n < 4; n++) {
                int j = j_blk + n * 16 + lq;       // row r = global i
                const float4 m2 = *reinterpret_cast<const float4*>(M2 + (size_t)(b * 128 + j) * 128 + o0);
                float r0 = fmaxf(acc[m][n][0] + bc.x + m2.x, 0.f);
                float r1 = fmaxf(acc[m][n][1] + bc.y + m2.y, 0.f);
                float r2 = fmaxf(acc[m][n][2] + bc.z + m2.z, 0.f);
                float r3 = fmaxf(acc[m][n][3] + bc.w + m2.w, 0.f);
                uint2 pk;
                pk.x = pk2(r0, r1);
                pk.y = pk2(r2, r3);
                *reinterpret_cast<uint2*>(X1 + j * 256 + ((((o0 >> 3) ^ (j & 7))) << 4) + (o0 & 7) * 2) = pk;
            }
        }
        __syncthreads();                   // barrier 2
    }

    // ======= stage 2: X0 = relu(X1@mlp1_w + mlp1_b) =======
    #pragma unroll
    for (int m = 0; m < 2; m++)
        #pragma unroll
        for (int n = 0; n < 4; n++) acc[m][n] = (f32x4){0.f, 0.f, 0.f, 0.f};
    mmv(Wm1, X1, acc, o_blk, j_blk, g, lq);
    {
        #pragma unroll
        for (int m = 0; m < 2; m++) {
            int o0 = o_blk + m * 16 + g * 4;
            const float4 bb = *reinterpret_cast<const float4*>(mlp1_b + o0);
            #pragma unroll
            for (int n = 0; n < 4; n++) {
                int j = j_blk + n * 16 + lq;
                float r0 = fmaxf(acc[m][n][0] + bb.x, 0.f);
                float r1 = fmaxf(acc[m][n][1] + bb.y, 0.f);
                float r2 = fmaxf(acc[m][n][2] + bb.z, 0.f);
                float r3 = fmaxf(acc[m][n][3] + bb.w, 0.f);
                uint2 pk;
                pk.x = pk2(r0, r1);
                pk.y = pk2(r2, r3);
                *reinterpret_cast<uint2*>(X0 + j * 256 + ((((o0 >> 3) ^ (j & 7))) << 4) + (o0 & 7) * 2) = pk;
            }
        }
        __syncthreads();                   // barrier 3
    }

    // ======= stage 3: X1 = X0@mlp2_w + mlp2_b (no relu) =======
    #pragma unroll
    for (int m = 0; m < 2; m++)
        #pragma unroll
        for (int n = 0; n < 4; n++) acc[m][n] = (f32x4){0.f, 0.f, 0.f, 0.f};
    mmv(Wm2, X0, acc, o_blk, j_blk, g, lq);
    {
        #pragma unroll
        for (int m = 0; m < 2; m++) {
            int o0 = o_blk + m * 16 + g * 4;
            const float4 bb = *reinterpret_cast<const float4*>(mlp2_b + o0);
            #pragma unroll
            for (int n = 0; n < 4; n++) {
                int j = j_blk + n * 16 + lq;
                float r0 = acc[m][n][0] + bb.x;
                float r1 = acc[m][n][1] + bb.y;
                float r2 = acc[m][n][2] + bb.z;
                float r3 = acc[m][n][3] + bb.w;
                uint2 pk;
                pk.x = pk2(r0, r1);
                pk.y = pk2(r2, r3);
                *reinterpret_cast<uint2*>(X1 + j * 256 + ((((o0 >> 3) ^ (j & 7))) << 4) + (o0 & 7) * 2) = pk;
            }
        }
        __syncthreads();                   // barrier 4 (also frees X0 for scratch)
    }

    // ======= fused epilogue: masked max over i + o2 head + LN -> out[b,jf,:] =======
    {
        float* scr  = reinterpret_cast<float*>(X0);   // X0 no longer needed
        float* aggs = scr;            // [4][128]
        float* fagg = scr + 512;      // [128]
        float* sums = scr + 640;      // [4][128]
        const int h = tid & 127, wv = tid >> 7;
        // prefetch finals for wave 0
        float o1zv0 = 0.f, o1zv1 = 0.f, ob0 = 0.f, ob1 = 0.f;
        float sc0 = 0.f, sc1 = 0.f, bi0 = 0.f, bi1 = 0.f;
        if (w == 0) {
            const float* o1p = O1z + (size_t)(b * 128 + jf) * 128;
            o1zv0 = o1p[l];      o1zv1 = o1p[l + 64];
            ob0 = o2_b[l];       ob1 = o2_b[l + 64];
            sc0 = nsc[l];        sc1 = nsc[l + 64];
            bi0 = nbi[l];        bi1 = nbi[l + 64];
        }
        {
            const int* acol = adj + b * 16384 + jf;
            float amax = -1e9f;
            #pragma unroll 8
            for (int s = 0; s < 32; s++) {
                int r = wv * 32 + s;
                ushort_t u = *reinterpret_cast<const ushort_t*>(
                    X1 + r * 256 + (((h >> 3) ^ (r & 7)) << 4) + (h & 7) * 2);
                amax = (acol[r * 128] == 1) ? fmaxf(amax, b2f(u)) : amax;
            }
            aggs[wv * 128 + h] = amax;
        }
        __syncthreads();                   // barrier 5
        if (tid < 128)
            fagg[tid] = fmaxf(fmaxf(aggs[tid], aggs[128 + tid]),
                              fmaxf(aggs[256 + tid], aggs[384 + tid]));
        __syncthreads();                   // barrier 6
        {
            float part = 0.f;
            const float* wcol = o2_w + h;
            #pragma unroll 8
            for (int k = wv * 32; k < wv * 32 + 32; k++)
                part = fmaf(fagg[k], wcol[k * 128], part);
            sums[wv * 128 + h] = part;
        }
        __syncthreads();                   // barrier 7
        if (w == 0) {    // lane l owns h=l and h=l+64; wave-internal reduce covers 128
            float v0 = fmaxf(ob0 + o1zv0 + sums[l] + sums[128 + l] + sums[256 + l] + sums[384 + l], 0.f);
            float v1 = fmaxf(ob1 + o1zv1 + sums[l + 64] + sums[128 + l + 64] + sums[256 + l + 64] + sums[384 + l + 64], 0.f);
            float s = v0 + v1, s2 = v0 * v0 + v1 * v1;
            #pragma unroll
            for (int off = 32; off >= 1; off >>= 1) {
                s  += __shfl_xor(s, off, 64);
                s2 += __shfl_xor(s2, off, 64);
            }
            const float mean = s * (1.0f / 128.0f);
            const float var = s2 * (1.0f / 128.0f) - mean * mean;
            const float rstd = rsqrtf(var + 1e-5f);
            float* dst = out + (size_t)(b * 128 + jf) * 128;
            dst[l]      = (v0 - mean) * rstd * sc0 + bi0;
            dst[l + 64] = (v1 - mean) * rstd * sc1 + bi1;
        }
    }
}

// ---------------------------------------------------------------------------
// triplet kernel: 1 jf per block, 512 threads; T1/T2/E3 read as bf16.
// ---------------------------------------------------------------------------
__global__ __launch_bounds__(512)
void tri_kernel(const ushort_t* __restrict__ T1buf, const ushort_t* __restrict__ T2buf,
                const ushort_t* __restrict__ E3buf, const float* __restrict__ o3_w,
                const float* __restrict__ o3_b, const float* __restrict__ scale,
                const float* __restrict__ bias, float* __restrict__ tri_out) {
    __shared__ __align__(16) float T1s[1024];
    __shared__ __align__(16) float E3s[1024];
    __shared__ __align__(16) float o3s[1024];
    __shared__ __align__(16) float Ps[4][128][8];
    const int b = blockIdx.x >> 7, jf = blockIdx.x & 127;
    const int tid = threadIdx.x;
    if (tid < 128) {
        uint4 u = reinterpret_cast<const uint4*>(T1buf + (size_t)(b * 128 + jf) * 1024)[tid];
        float* d = &T1s[tid * 8];
        d[0] = b2f((ushort_t)u.x); d[1] = b2f((ushort_t)(u.x >> 16));
        d[2] = b2f((ushort_t)u.y); d[3] = b2f((ushort_t)(u.y >> 16));
        d[4] = b2f((ushort_t)u.z); d[5] = b2f((ushort_t)(u.z >> 16));
        d[6] = b2f((ushort_t)u.w); d[7] = b2f((ushort_t)(u.w >> 16));
    } else if (tid < 256) {
        int t = tid - 128;
        uint4 u = reinterpret_cast<const uint4*>(E3buf + (size_t)(b * 128 + jf) * 1024)[t];
        float* d = &E3s[t * 8];
        d[0] = b2f((ushort_t)u.x); d[1] = b2f((ushort_t)(u.x >> 16));
        d[2] = b2f((ushort_t)u.y); d[3] = b2f((ushort_t)(u.y >> 16));
        d[4] = b2f((ushort_t)u.z); d[5] = b2f((ushort_t)(u.z >> 16));
        d[6] = b2f((ushort_t)u.w); d[7] = b2f((ushort_t)(u.w >> 16));
    } else {
        int t = tid - 256;   // 256 threads x float4 = 1024 floats
        reinterpret_cast<float4*>(o3s)[t] = reinterpret_cast<const float4*>(o3_w)[t];
    }
    __syncthreads();

    {
        const int kf = tid & 127, ih = tid >> 7;      // ih 0..3
        float a8[8];
        #pragma unroll
        for (int t = 0; t < 8; t++) a8[t] = -3.0e38f;
        const uint4* t2p = reinterpret_cast<const uint4*>(T2buf + (size_t)b * 131072);
        #pragma unroll 4
        for (int ii = 0; ii < 32; ++ii) {
            const int i = ih * 32 + ii;
            uint4 u = t2p[i * 128 + kf];
            const float* t1r = &T1s[i * 8];
            a8[0] = fmaxf(a8[0], t1r[0] + b2f((ushort_t)u.x));
            a8[1] = fmaxf(a8[1], t1r[1] + b2f((ushort_t)(u.x >> 16)));
            a8[2] = fmaxf(a8[2], t1r[2] + b2f((ushort_t)u.y));
            a8[3] = fmaxf(a8[3], t1r[3] + b2f((ushort_t)(u.y >> 16)));
            a8[4] = fmaxf(a8[4], t1r[4] + b2f((ushort_t)u.z));
            a8[5] = fmaxf(a8[5], t1r[5] + b2f((ushort_t)(u.z >> 16)));
            a8[6] = fmaxf(a8[6], t1r[6] + b2f((ushort_t)u.w));
            a8[7] = fmaxf(a8[7], t1r[7] + b2f((ushort_t)(u.w >> 16)));
        }
        #pragma unroll
        for (int t = 0; t < 8; t++) Ps[ih][kf][t] = a8[t];
    }
    __syncthreads();

    const int w = tid >> 6, l = tid & 63;
    const float ob0 = o3_b[l],     ob1 = o3_b[l + 64];
    const float sc0 = scale[l],    sc1 = scale[l + 64];
    const float bi0 = bias[l],     bi1 = bias[l + 64];
    for (int kk = 0; kk < 16; ++kk) {
        const int kf = w * 16 + kk;
        float m8[8];
        #pragma unroll
        for (int t = 0; t < 8; t++)
            m8[t] = fmaxf(fmaxf(Ps[0][kf][t], Ps[1][kf][t]),
                          fmaxf(Ps[2][kf][t], Ps[3][kf][t])) + E3s[kf * 8 + t];
        float v0 = ob0, v1 = ob1;
        #pragma unroll
        for (int t = 0; t < 8; t++) {
            v0 = fmaf(m8[t], o3s[t * 128 + l], v0);
            v1 = fmaf(m8[t], o3s[t * 128 + l + 64], v1);
        }
        v0 = fmaxf(v0, 0.0f);
        v1 = fmaxf(v1, 0.0f);
        float s = v0 + v1, s2 = v0 * v0 + v1 * v1;
        #pragma unroll
        for (int off = 32; off >= 1; off >>= 1) {
            s  += __shfl_xor(s, off, 64);
            s2 += __shfl_xor(s2, off, 64);
        }
        const float mean = s * (1.0f / 128.0f);
        const float var = s2 * (1.0f / 128.0f) - mean * mean;
        const float rstd = rsqrtf(var + 1e-5f);
        float* dst = tri_out + (size_t)((b * 128 + jf) * 128 + kf) * 128;
        dst[l]      = (v0 - mean) * rstd * sc0 + bi0;
        dst[l + 64] = (v1 - mean) * rstd * sc1 + bi1;
    }
}

// ---------------------------------------------------------------------------
extern "C" void kernel_launch(void* const* d_in, const int* in_sizes, int n_in,
                              void* d_out, int out_size, void* d_ws, size_t ws_size,
                              hipStream_t stream) {
    const float* node_fts  = (const float*)d_in[0];
    const float* edge_fts  = (const float*)d_in[1];
    const float* graph_fts = (const float*)d_in[2];
    const float* hidden    = (const float*)d_in[3];
    const int*   adj       = (const int*)d_in[4];
    const float* m1_w = (const float*)d_in[5],  *m1_b = (const float*)d_in[6];
    const float* m2_w = (const float*)d_in[7],  *m2_b = (const float*)d_in[8];
    const float* me_w = (const float*)d_in[9],  *me_b = (const float*)d_in[10];
    const float* mg_w = (const float*)d_in[11], *mg_b = (const float*)d_in[12];
    const float* mlp1_w = (const float*)d_in[13], *mlp1_b = (const float*)d_in[14];
    const float* mlp2_w = (const float*)d_in[15], *mlp2_b = (const float*)d_in[16];
    const float* o1_w = (const float*)d_in[17], *o1_b = (const float*)d_in[18];
    const float* o2_w = (const float*)d_in[19], *o2_b = (const float*)d_in[20];
    const float* t1_w = (const float*)d_in[21], *t1_b = (const float*)d_in[22];
    const float* t2_w = (const float*)d_in[23], *t2_b = (const float*)d_in[24];
    const float* te1_w = (const float*)d_in[25], *te1_b = (const float*)d_in[26];
    const float* te2_w = (const float*)d_in[27], *te2_b = (const float*)d_in[28];
    const float* te3_w = (const float*)d_in[29], *te3_b = (const float*)d_in[30];
    const float* tg_w = (const float*)d_in[31], *tg_b = (const float*)d_in[32];
    const float* o3_w = (const float*)d_in[33], *o3_b = (const float*)d_in[34];
    const float* norm_scale = (const float*)d_in[35];
    const float* norm_bias  = (const float*)d_in[36];

    char* w8 = (char*)d_ws;
    float*    M1    = (float*)(w8 + 0);          // 256 KB
    float*    M2    = (float*)(w8 + 262144);     // 256 KB
    float*    O1z   = (float*)(w8 + 524288);     // 256 KB
    float*    T1v   = (float*)(w8 + 786432);     // 16 KB
    float*    TT2   = (float*)(w8 + 802816);     // 16 KB
    ushort_t* Wme   = (ushort_t*)(w8 + 819200);  // 32 KB
    ushort_t* Wm1   = (ushort_t*)(w8 + 851968);  // 32 KB
    ushort_t* Wm2   = (ushort_t*)(w8 + 884736);  // 32 KB
    ushort_t* TEt   = (ushort_t*)(w8 + 917504);  // 8 KB
    ushort_t* T1buf = (ushort_t*)(w8 + 17702912);// 1 MB (bf16)
    ushort_t* T2buf = (ushort_t*)(w8 + 19800064);// 1 MB (bf16)
    ushort_t* E3buf = (ushort_t*)(w8 + 21897216);// 1 MB (bf16)
    ushort_t* Wnt   = (ushort_t*)(w8 + 23994368);// 208 KB
    float*    G1    = (float*)(w8 + 24207360);   // 2 KB
    float*    TG    = (float*)(w8 + 24209408);   // 128 B

    float* out_p  = (float*)d_out;            // [4,128,128]
    float* tri_p  = (float*)d_out + 65536;    // [4,128,128,128]

    prep_kernel<<<627, 256, 0, stream>>>(m1_w, m2_w, o1_w, t1_w, t2_w,
                                         me_w, mlp1_w, mlp2_w, te1_w, te2_w, te3_w,
                                         graph_fts, mg_w, mg_b, m1_b, tg_w, t2_b, tg_b,
                                         Wnt, Wme, Wm1, Wm2, TEt, G1, TG);
    node_gemm<<<32, 256, 0, stream>>>(node_fts, hidden, Wnt, G1, m2_b, o1_b, t1_b, TG,
                                      M1, M2, O1z, T1v, TT2);
    edge_kernel<<<512, 512, 0, stream>>>(edge_fts, Wme, me_b, Wm1, mlp1_b, Wm2, mlp2_b,
                                         TEt, te1_b, te2_b, te3_b,
                                         M1, M2, T1v, TT2,
                                         adj, O1z, o2_w, o2_b, norm_scale, norm_bias,
                                         out_p, T1buf, T2buf, E3buf);
    tri_kernel<<<512, 512, 0, stream>>>(T1buf, T2buf, E3buf, o3_w, o3_b,
                                        norm_scale, norm_bias, tri_p);
}